// Round 2
// baseline (11938.288 us; speedup 1.0000x reference)
//
#include <hip/hip_runtime.h>
#include <hip/hip_fp16.h>
#include <math.h>

typedef _Float16 h2 __attribute__((ext_vector_type(2)));
typedef _Float16 h8 __attribute__((ext_vector_type(8)));
typedef float    f4 __attribute__((ext_vector_type(4)));
typedef unsigned short     u16;
typedef unsigned int       u32;
typedef unsigned long long u64;

#define BB 64
#define TT 512
#define DD 256
#define UU 512

#define NBLK 64
#define CPB  44   // packed gate-cols per block: 8*{fs,fl,al,o,WCh} + 4 m
#define XPB  36   // of those, cols with an x-contribution (32 gate + 4 m)
#define UPB  8    // h/c columns owned per block
#define MPB  4    // m (x-dim) columns owned per block
#define NJ   2816
#define NJX  2304

// ---------- ws layout (bytes) ----------
#define OFF_W1   0ull                              // f16 [2816][512] packed, K-contig
#define OFF_W2   (OFF_W1 + 2816ull*512*2)          // f16 [512][256]
#define OFF_WX   (OFF_W2 + 512ull*256*2)           // f16 [2304][256] packed
#define OFF_B1   (OFF_WX + 2304ull*256*2)          // f32 [2816] packed
#define OFF_HB   (OFF_B1 + 2816ull*4)              // u64 [64][256] tagged h records
#define OFF_MX   (OFF_HB + 64ull*256*8)            // u64 [64][128] tagged mod_x records
#define OFF_CTR  (OFF_MX + 64ull*128*8)            // (legacy slot, unused)
#define OFF_XPRE (OFF_CTR + 16400ull*4)            // f16 [512][2304][64]
#define WS_FULL  (OFF_XPRE + 512ull*2304*64*2)     // ~155.7 MB

__device__ __forceinline__ float sigf(float v)     { return 1.0f / (1.0f + __expf(-v)); }
__device__ __forceinline__ float tanhfast(float v) { return 1.0f - 2.0f / (__expf(2.0f * v) + 1.0f); }

// [2 x f16 payload | u32 tag] in one single-copy-atomic u64
__device__ __forceinline__ u64 pack_rec(float a, float b, u32 tag) {
    _Float16 ha = (_Float16)a, hb = (_Float16)b;
    u16 ua, ub;
    __builtin_memcpy(&ua, &ha, 2);
    __builtin_memcpy(&ub, &hb, 2);
    return (u64)((u32)ua | ((u32)ub << 16)) | ((u64)tag << 32);
}

// packed-order helpers (fallback path)
__device__ __forceinline__ int pk5(int g, int u) { return (u >> 3) * 44 + g * 8 + (u & 7); }
__device__ __forceinline__ int pkm(int d)        { return (d >> 2) * 44 + 40 + (d & 3); }

// =====================================================================
// Kernel 1: repack weights into packed block-sliced f16 layouts + zero
// the tagged record buffers (tags from a previous launch would alias).
// =====================================================================
__global__ void repack_kernel(const float* __restrict__ Wfs, const float* __restrict__ Wfl,
                              const float* __restrict__ Wal, const float* __restrict__ Wm,
                              const float* __restrict__ WC,  const float* __restrict__ Wo,
                              const float* __restrict__ bfs, const float* __restrict__ bfl,
                              const float* __restrict__ bal, const float* __restrict__ bm,
                              const float* __restrict__ bC,  const float* __restrict__ bo,
                              _Float16* __restrict__ W1, _Float16* __restrict__ W2,
                              _Float16* __restrict__ WxT, float* __restrict__ b1,
                              u64* __restrict__ recs)
{
    const int stride = gridDim.x * blockDim.x;
    const int idx = blockIdx.x * blockDim.x + threadIdx.x;

    for (int i = idx; i < 2816 * 512; i += stride) {
        int J = i >> 9, k = i & 511;
        int blk = J / 44, c = J - blk * 44;
        float v;
        if (c < 40) {
            int grp = c >> 3, u = blk * 8 + (c & 7);
            const float* Wg = (grp == 0) ? Wfs : (grp == 1) ? Wfl : (grp == 2) ? Wal : (grp == 3) ? Wo : WC;
            v = Wg[(size_t)k * 512 + u];
        } else {
            int d = blk * 4 + (c - 40);
            v = Wm[(size_t)k * 256 + d];
        }
        W1[i] = (_Float16)v;
    }
    for (int i = idx; i < 512 * 256; i += stride) {
        int u = i >> 8, dd = i & 255;
        W2[i] = (_Float16)WC[(size_t)(512 + dd) * 512 + u];
    }
    for (int i = idx; i < 2304 * 256; i += stride) {
        int Jx = i >> 8, k2 = i & 255;
        int blk = Jx / 36, lc = Jx - blk * 36;
        float v;
        if (lc < 32) {
            int grp = lc >> 3, u = blk * 8 + (lc & 7);
            const float* Wg = (grp == 0) ? Wfs : (grp == 1) ? Wfl : (grp == 2) ? Wal : Wo;
            v = Wg[(size_t)(512 + k2) * 512 + u];
        } else {
            int d = blk * 4 + (lc - 32);
            v = Wm[(size_t)(512 + k2) * 256 + d];
        }
        WxT[i] = (_Float16)v;
    }
    for (int J = idx; J < 2816; J += stride) {
        int blk = J / 44, c = J - blk * 44;
        float v;
        if (c < 40) {
            int grp = c >> 3, u = blk * 8 + (c & 7);
            v = (grp == 0) ? bfs[u] : (grp == 1) ? bfl[u] : (grp == 2) ? bal[u] : (grp == 3) ? bo[u] : bC[u];
        } else {
            v = bm[blk * 4 + (c - 40)];
        }
        b1[J] = v;
    }
    // zero tagged h (64*256) + mx (64*128) records: 24576 u64
    for (int i = idx; i < 24576; i += stride) recs[i] = 0ull;
}

// =====================================================================
// Kernel 2: Xpre = x @ W_x via MFMA.  [32768,256]@[256,2304] -> f16
// output layout [t][Jx][b].
// =====================================================================
__global__ __launch_bounds__(256) void xpre_kernel(const float* __restrict__ x,
                                                   const _Float16* __restrict__ WxT,
                                                   _Float16* __restrict__ Xpre)
{
    __shared__ _Float16 As[128 * 32];
    __shared__ _Float16 Bs[128 * 32];

    const int tid  = threadIdx.x;
    const int lane = tid & 63;
    const int w    = tid >> 6;
    const int wm   = w >> 1, wn = w & 1;
    const int quad = lane >> 4, l16 = lane & 15;
    const int row0 = blockIdx.x * 128;
    const int n0   = blockIdx.y * 128;

    f4 acc[4][4];
    for (int i = 0; i < 4; ++i)
        for (int j = 0; j < 4; ++j)
            acc[i][j] = (f4){0.f, 0.f, 0.f, 0.f};

    for (int kt = 0; kt < 8; ++kt) {
        const int k0 = kt * 32;
        {
            int r  = tid >> 3;
            int cg = (tid & 7) * 4;
            for (int rr = r; rr < 128; rr += 32) {
                f4 v = *(const f4*)&x[(size_t)(row0 + rr) * 256 + k0 + cg];
                As[rr * 32 + cg + 0] = (_Float16)v.x;
                As[rr * 32 + cg + 1] = (_Float16)v.y;
                As[rr * 32 + cg + 2] = (_Float16)v.z;
                As[rr * 32 + cg + 3] = (_Float16)v.w;
            }
        }
        {
            int r   = tid & 127;
            int seg = (tid >> 7) * 16;
            const _Float16* src = &WxT[(size_t)(n0 + r) * 256 + k0 + seg];
            *(f4*)&Bs[r * 32 + seg]     = *(const f4*)src;
            *(f4*)&Bs[r * 32 + seg + 8] = *(const f4*)(src + 8);
        }
        __syncthreads();

        h8 af[4], bfr[4];
#pragma unroll
        for (int f = 0; f < 4; ++f) {
            af[f]  = *(const h8*)&As[(wm * 64 + f * 16 + l16) * 32 + quad * 8];
            bfr[f] = *(const h8*)&Bs[(wn * 64 + f * 16 + l16) * 32 + quad * 8];
        }
#pragma unroll
        for (int fm = 0; fm < 4; ++fm)
#pragma unroll
            for (int fn = 0; fn < 4; ++fn)
                acc[fm][fn] = __builtin_amdgcn_mfma_f32_16x16x32_f16(af[fm], bfr[fn], acc[fm][fn], 0, 0, 0);
        __syncthreads();
    }

#pragma unroll
    for (int fm = 0; fm < 4; ++fm)
#pragma unroll
        for (int fn = 0; fn < 4; ++fn)
#pragma unroll
            for (int r = 0; r < 4; ++r) {
                int rr = row0 + wm * 64 + fm * 16 + quad * 4 + r;  // x row = b*T+t
                int J  = n0 + wn * 64 + fn * 16 + l16;
                int b = rr >> 9, tt = rr & 511;
                Xpre[((size_t)tt * NJX + J) * 64 + b] = (_Float16)acc[fm][fn][r];
            }
}

// =====================================================================
// Kernel 3: cooperative recurrent scan with single-RTT tagged records.
// 64 blocks x 256 thr. Per step:
//   per-thread gather of 64 tagged h records (relaxed agent atomics ->
//   IC direct, tag==t+1 validates; retry on stale) -> acc2 -> quad2
//   lanes publish mod_x as tagged records (fire-and-forget, no drain)
//   -> acc0/acc1 -> barrier -> elementwise -> barrier -> per-thread
//   gather of 32 tagged mx records -> GEMM2 -> update -> publish h as
//   tagged records (tag t+2, fire-and-forget) -> out store -> loop.
// Only 2 barriers/step; zero flag traffic; zero producer drains.
// Overwrite safety: A can't publish h(t+1) before consuming mx(t+1)
// from B, which requires B to have consumed h(t) — the recurrence's own
// dependencies double-buffer the records.
// =====================================================================
__global__ __launch_bounds__(256, 1) void rnn_coop(
    const float* __restrict__ x, const float* __restrict__ h0, const float* __restrict__ c0,
    const _Float16* __restrict__ W1, const _Float16* __restrict__ W2,
    const float* __restrict__ b1, const _Float16* __restrict__ Xpre,
    u64* __restrict__ hbufT, u64* __restrict__ mxbufT,
    float* __restrict__ out)
{
    __shared__ __align__(16) _Float16 sW1[48 * 512];  // 48 KB, resident all steps
    __shared__ float sS[48 * 68];                     // stride 68: 2-way max (free)
    __shared__ float sF[8 * 64];
    __shared__ float sO[8 * 64];
    __shared__ float sCP[8 * 64];
    __shared__ float sC[8 * 64];
    __shared__ float sB1[44];

    const int tid  = threadIdx.x;
    const int blk  = blockIdx.x;
    const int lane = tid & 63;
    const int w    = tid >> 6;
    const int l16  = lane & 15;
    const int quad = lane >> 4;
    const int swz  = l16 & 7;
    const int br   = w * 16 + l16;   // batch row owned in MFMA B-frags

    // ---- stage W1 slice (44 rows + 4 zero-pad) with chunk swizzle ----
    for (int idx = tid; idx < 48 * 64; idx += 256) {
        int r = idx >> 6, j = idx & 63;
        h8 v = {};
        if (r < CPB) v = *(const h8*)(W1 + ((size_t)(blk * CPB + r) * 512 + j * 8));
        *(h8*)&sW1[(r * 64 + (j ^ (r & 7))) * 8] = v;
    }
    // ---- W2 A-frags in registers for all steps (rows u<8, pad to 16) ----
    h8 af2[8];
#pragma unroll
    for (int ks = 0; ks < 8; ++ks) {
        af2[ks] = (h8){};
        if (l16 < 8)
            af2[ks] = *(const h8*)(W2 + (size_t)(blk * UPB + l16) * 256 + ks * 32 + quad * 8);
    }
    if (tid < CPB) sB1[tid] = b1[blk * CPB + tid];
    // ---- init c (block-local) ----
    for (int idx = tid; idx < UPB * 64; idx += 256) {
        int u = idx >> 6, b = idx & 63;
        sC[u * 64 + b] = c0[b * UU + blk * UPB + u];
    }
    // ---- publish our h0 slice as tagged records (tag 1), no drain ----
    if (tid < 128) {
        int q = tid >> 6, b = tid & 63;
        float v0 = h0[b * UU + blk * UPB + q * 4 + 0];
        float v1 = h0[b * UU + blk * UPB + q * 4 + 1];
        float v2 = h0[b * UU + blk * UPB + q * 4 + 2];
        float v3 = h0[b * UU + blk * UPB + q * 4 + 3];
        __hip_atomic_store(hbufT + (size_t)b * 256 + blk * 4 + q * 2 + 0, pack_rec(v0, v1, 1u),
                           __ATOMIC_RELAXED, __HIP_MEMORY_SCOPE_AGENT);
        __hip_atomic_store(hbufT + (size_t)b * 256 + blk * 4 + q * 2 + 1, pack_rec(v2, v3, 1u),
                           __ATOMIC_RELAXED, __HIP_MEMORY_SCOPE_AGENT);
    }
    __syncthreads();                      // LDS init (sW1, sB1, sC) ready

    for (int t = 0; t < TT; ++t) {
        // ---- prefetch read-only operands (overlap the gather) ----
        const _Float16* xp = Xpre + ((size_t)t * NJX + blk * XPB) * 64;
        float pfs[2], pfl[2], pal[2], pov[2];
#pragma unroll
        for (int i = 0; i < 2; ++i) {
            int u = w * 2 + i;
            pfs[i] = (float)xp[(size_t)u * 64 + lane];
            pfl[i] = (float)xp[(size_t)(8 + u) * 64 + lane];
            pal[i] = (float)xp[(size_t)(16 + u) * 64 + lane];
            pov[i] = (float)xp[(size_t)(24 + u) * 64 + lane];
        }
        float pxm[4] = {0.f, 0.f, 0.f, 0.f};
        f4 pxv = {0.f, 0.f, 0.f, 0.f};
        if (quad == 2) {
#pragma unroll
            for (int r = 0; r < 4; ++r)
                pxm[r] = (float)xp[(size_t)(32 + r) * 64 + br];
            pxv = *(const f4*)&x[((size_t)br * TT + t) * DD + blk * MPB];
        }

        // ---- per-thread tagged gather of h(t-1): ONE IC round-trip ----
        u64 rec[16][4];
        {
            u64* hT = hbufT + (size_t)br * 256;
            const u32 expt = (u32)t + 1u;
            bool ok; u32 guard = 0;
            do {
#pragma unroll
                for (int ks = 0; ks < 16; ++ks) {
                    const int base = (ks * 4 + quad) * 4;
#pragma unroll
                    for (int j = 0; j < 4; ++j)
                        rec[ks][j] = __hip_atomic_load(hT + base + j,
                                                       __ATOMIC_RELAXED, __HIP_MEMORY_SCOPE_AGENT);
                }
                ok = true;
#pragma unroll
                for (int ks = 0; ks < 16; ++ks)
#pragma unroll
                    for (int j = 0; j < 4; ++j)
                        ok = ok && ((u32)(rec[ks][j] >> 32) == expt);
                if (!ok) __builtin_amdgcn_s_sleep(1);
            } while (!ok && ++guard < 2000000u);
        }
        h8 bf[16];
#pragma unroll
        for (int ks = 0; ks < 16; ++ks) {
            u32 d[4] = {(u32)rec[ks][0], (u32)rec[ks][1], (u32)rec[ks][2], (u32)rec[ks][3]};
            __builtin_memcpy(&bf[ks], d, 16);
        }

        // ---- acc2 first: cols 32..47 = WCh(32..39) + m(40..43) ----
        f4 acc2 = {0.f, 0.f, 0.f, 0.f};
#pragma unroll
        for (int ks = 0; ks < 16; ++ks) {
            int jx = (ks * 4 + quad) ^ swz;
            h8 a2 = *(const h8*)&sW1[((32 + l16) * 64 + jx) * 8];
            acc2 = __builtin_amdgcn_mfma_f32_16x16x32_f16(a2, bf[ks], acc2, 0, 0, 0);
        }
        // WCh rows 32..39 to LDS (read at elementwise, after barrier B)
        if (quad < 2) {
#pragma unroll
            for (int r = 0; r < 4; ++r)
                sS[(32 + quad * 4 + r) * 68 + br] = acc2[r];
        }
        // mod_x straight from registers: quad2 lane holds preact[d=blk*4+r][br].
        // Publish as tagged records — fire-and-forget, no drain, no flag.
        if (quad == 2) {
            const u32 tagm = (u32)t + 1u;
#pragma unroll
            for (int p = 0; p < 2; ++p) {
                float m0 = sigf(acc2[2 * p]     + sB1[40 + 2 * p]     + pxm[2 * p])     * pxv[2 * p];
                float m1 = sigf(acc2[2 * p + 1] + sB1[40 + 2 * p + 1] + pxm[2 * p + 1]) * pxv[2 * p + 1];
                __hip_atomic_store(mxbufT + (size_t)br * 128 + blk * 2 + p, pack_rec(m0, m1, tagm),
                                   __ATOMIC_RELAXED, __HIP_MEMORY_SCOPE_AGENT);
            }
        }

        // ---- acc0/acc1: cols 0..31 (fs,fl,al,o), reuse bf regs ----
        f4 acc0 = {0.f, 0.f, 0.f, 0.f}, acc1 = {0.f, 0.f, 0.f, 0.f};
#pragma unroll
        for (int ks = 0; ks < 16; ++ks) {
            int jx = (ks * 4 + quad) ^ swz;
            h8 a0 = *(const h8*)&sW1[((     l16) * 64 + jx) * 8];
            h8 a1 = *(const h8*)&sW1[((16 + l16) * 64 + jx) * 8];
            acc0 = __builtin_amdgcn_mfma_f32_16x16x32_f16(a0, bf[ks], acc0, 0, 0, 0);
            acc1 = __builtin_amdgcn_mfma_f32_16x16x32_f16(a1, bf[ks], acc1, 0, 0, 0);
        }
#pragma unroll
        for (int r = 0; r < 4; ++r) {
            sS[(     quad * 4 + r) * 68 + br] = acc0[r];
            sS[(16 + quad * 4 + r) * 68 + br] = acc1[r];
        }
        __syncthreads();                  // B: sS ready for cross-wave reads

        // ---- elementwise: f/o gates + cpre ----
#pragma unroll
        for (int i = 0; i < 2; ++i) {
            int u = w * 2 + i;
            float fs = sigf(sS[u * 68 + lane]        + sB1[u]      + pfs[i]);
            float fl = sigf(sS[(8 + u) * 68 + lane]  + sB1[8 + u]  + pfl[i]);
            float al = sigf(sS[(16 + u) * 68 + lane] + sB1[16 + u] + pal[i]);
            sF[u * 64 + lane]  = al * fs + (1.0f - al) * fl;
            sO[u * 64 + lane]  = sigf(sS[(24 + u) * 68 + lane] + sB1[24 + u] + pov[i]);
            sCP[u * 64 + lane] = sS[(32 + u) * 68 + lane] + sB1[32 + u];
        }
        __syncthreads();                  // C: sF/sO/sCP ready

        // ---- per-thread tagged gather of mod_x: ONE IC round-trip ----
        u64 rec2[8][4];
        {
            u64* mT = mxbufT + (size_t)br * 128;
            const u32 expt = (u32)t + 1u;
            bool ok; u32 guard = 0;
            do {
#pragma unroll
                for (int ks = 0; ks < 8; ++ks) {
                    const int base = (ks * 4 + quad) * 4;
#pragma unroll
                    for (int j = 0; j < 4; ++j)
                        rec2[ks][j] = __hip_atomic_load(mT + base + j,
                                                        __ATOMIC_RELAXED, __HIP_MEMORY_SCOPE_AGENT);
                }
                ok = true;
#pragma unroll
                for (int ks = 0; ks < 8; ++ks)
#pragma unroll
                    for (int j = 0; j < 4; ++j)
                        ok = ok && ((u32)(rec2[ks][j] >> 32) == expt);
                if (!ok) __builtin_amdgcn_s_sleep(1);
            } while (!ok && ++guard < 2000000u);
        }

        // ---- GEMM2: W2(regs) x mod_x(tagged regs); update; publish h ----
        {
            f4 aq = {0.f, 0.f, 0.f, 0.f};
#pragma unroll
            for (int ks = 0; ks < 8; ++ks) {
                u32 d[4] = {(u32)rec2[ks][0], (u32)rec2[ks][1], (u32)rec2[ks][2], (u32)rec2[ks][3]};
                h8 bf2; __builtin_memcpy(&bf2, d, 16);
                aq = __builtin_amdgcn_mfma_f32_16x16x32_f16(af2[ks], bf2, aq, 0, 0, 0);
            }
            if (quad < 2) {
                const int u0 = quad * 4;
                float hv[4];
#pragma unroll
                for (int r = 0; r < 4; ++r) {
                    int u = u0 + r;
                    float ch = tanhfast(aq[r] + sCP[u * 64 + br]);
                    float f  = sF[u * 64 + br];
                    float c  = f * sC[u * 64 + br] + (1.0f - f) * ch;
                    sC[u * 64 + br] = c;
                    hv[r] = sO[u * 64 + br] * tanhfast(c);
                }
                const u32 tagh = (u32)t + 2u;
                __hip_atomic_store(hbufT + (size_t)br * 256 + blk * 4 + quad * 2 + 0,
                                   pack_rec(hv[0], hv[1], tagh),
                                   __ATOMIC_RELAXED, __HIP_MEMORY_SCOPE_AGENT);
                __hip_atomic_store(hbufT + (size_t)br * 256 + blk * 4 + quad * 2 + 1,
                                   pack_rec(hv[2], hv[3], tagh),
                                   __ATOMIC_RELAXED, __HIP_MEMORY_SCOPE_AGENT);
                f4 ovec = {hv[0], hv[1], hv[2], hv[3]};
                __builtin_nontemporal_store(ovec, (f4*)&out[((size_t)br * TT + t) * UU + blk * UPB + u0]);
            }
        }
        // no end-of-step barrier: barrier C protects sF/sO/sCP/sS reuse,
        // tags protect the global records.
    }
}

// =====================================================================
// Fallback (small ws): per-batch dot2 scan on packed weights.
// =====================================================================
__global__ __launch_bounds__(704) void rnn_fb(const float* __restrict__ x,
                                              const float* __restrict__ h0,
                                              const float* __restrict__ c0,
                                              const _Float16* __restrict__ W1,
                                              const _Float16* __restrict__ W2,
                                              const _Float16* __restrict__ WxT,
                                              const float* __restrict__ b1g,
                                              float* __restrict__ out)
{
    __shared__ float g_ld[2816];
    __shared__ float b1_ld[2816];
    __shared__ float h_ld[512];
    __shared__ float x_ld[256];
    __shared__ float f_ld[512];
    __shared__ float o_ld[512];
    __shared__ float c_ld[512];
    __shared__ __align__(16) h2 hx_h2[256];
    __shared__ __align__(16) h2 x16_h2[128];
    __shared__ __align__(16) h2 modx_h2[128];

    const int tid = threadIdx.x;
    const int b   = blockIdx.x;
    const int j0  = tid * 4;
    const int c   = j0 % 44;
    const bool hasx = (c < 32) || (c >= 40);
    const int Jx0 = (j0 / 44) * 36 + (c < 32 ? c : c - 8);

    for (int j = tid; j < 2816; j += 704) b1_ld[j] = b1g[j];
    if (tid < 512) {
        h_ld[tid] = h0[b * 512 + tid];
        c_ld[tid] = c0[b * 512 + tid];
    }
    __syncthreads();

    const f4* __restrict__ w1r = (const f4*)(W1 + (size_t)j0 * 512);
    const float* __restrict__ xrow = x + (size_t)b * TT * DD;
    float* __restrict__ orow = out + (size_t)b * TT * UU;

    for (int t = 0; t < TT; ++t) {
        if (tid < 256) {
            h2 p; p[0] = (_Float16)h_ld[2 * tid]; p[1] = (_Float16)h_ld[2 * tid + 1];
            hx_h2[tid] = p;
        } else if (tid < 384) {
            int i = tid - 256;
            float v0 = xrow[t * DD + 2 * i];
            float v1 = xrow[t * DD + 2 * i + 1];
            x_ld[2 * i] = v0; x_ld[2 * i + 1] = v1;
            h2 p; p[0] = (_Float16)v0; p[1] = (_Float16)v1;
            x16_h2[i] = p;
        }
        __syncthreads();

        float a0 = b1_ld[j0], a1 = b1_ld[j0 + 1], a2 = b1_ld[j0 + 2], a3 = b1_ld[j0 + 3];
        if (hasx) {
            const f4* xr0 = (const f4*)(WxT + (size_t)Jx0 * 256);
            const f4* xr1 = xr0 + 32;
            const f4* xr2 = xr0 + 64;
            const f4* xr3 = xr0 + 96;
            const f4* xv4 = (const f4*)x16_h2;
#pragma unroll 4
            for (int kc = 0; kc < 32; ++kc) {
                f4 xv = xv4[kc];
                f4 w0 = xr0[kc], w1 = xr1[kc], w2 = xr2[kc], w3 = xr3[kc];
                const h2* xpv = (const h2*)&xv;
                const h2* p0 = (const h2*)&w0; const h2* p1 = (const h2*)&w1;
                const h2* p2 = (const h2*)&w2; const h2* p3 = (const h2*)&w3;
#pragma unroll
                for (int u = 0; u < 4; ++u) {
                    a0 = __builtin_amdgcn_fdot2(p0[u], xpv[u], a0, false);
                    a1 = __builtin_amdgcn_fdot2(p1[u], xpv[u], a1, false);
                    a2 = __builtin_amdgcn_fdot2(p2[u], xpv[u], a2, false);
                    a3 = __builtin_amdgcn_fdot2(p3[u], xpv[u], a3, false);
                }
            }
        }
        {
            const f4* hx4 = (const f4*)hx_h2;
            const f4* r0 = w1r;
            const f4* r1 = w1r + 64;
            const f4* r2 = w1r + 128;
            const f4* r3 = w1r + 192;
#pragma unroll 4
            for (int kc = 0; kc < 64; ++kc) {
                f4 hv = hx4[kc];
                f4 w0 = r0[kc], w1 = r1[kc], w2 = r2[kc], w3 = r3[kc];
                const h2* hp = (const h2*)&hv;
                const h2* p0 = (const h2*)&w0; const h2* p1 = (const h2*)&w1;
                const h2* p2 = (const h2*)&w2; const h2* p3 = (const h2*)&w3;
#pragma unroll
                for (int u = 0; u < 4; ++u) {
                    a0 = __builtin_amdgcn_fdot2(p0[u], hp[u], a0, false);
                    a1 = __builtin_amdgcn_fdot2(p1[u], hp[u], a1, false);
                    a2 = __builtin_amdgcn_fdot2(p2[u], hp[u], a2, false);
                    a3 = __builtin_amdgcn_fdot2(p3[u], hp[u], a3, false);
                }
            }
        }
        g_ld[j0] = a0; g_ld[j0 + 1] = a1; g_ld[j0 + 2] = a2; g_ld[j0 + 3] = a3;
        __syncthreads();

        if (tid < 128) {
            float m0 = sigf(g_ld[pkm(2 * tid)]);
            float m1 = sigf(g_ld[pkm(2 * tid + 1)]);
            h2 p;
            p[0] = (_Float16)(m0 * x_ld[2 * tid]);
            p[1] = (_Float16)(m1 * x_ld[2 * tid + 1]);
            modx_h2[tid] = p;
        } else if (tid < 640) {
            int u = tid - 128;
            float fs = sigf(g_ld[pk5(0, u)]);
            float fl = sigf(g_ld[pk5(1, u)]);
            float al = sigf(g_ld[pk5(2, u)]);
            f_ld[u] = al * fs + (1.0f - al) * fl;
            o_ld[u] = sigf(g_ld[pk5(3, u)]);
        }
        __syncthreads();

        if (tid < 512) {
            float s = g_ld[pk5(4, tid)];
            const f4* w2r = (const f4*)(W2 + (size_t)tid * 256);
            const f4* mx4 = (const f4*)modx_h2;
#pragma unroll 4
            for (int kc = 0; kc < 32; ++kc) {
                f4 wv = w2r[kc];
                f4 mv = mx4[kc];
                const h2* wp = (const h2*)&wv;
                const h2* mp = (const h2*)&mv;
#pragma unroll
                for (int u = 0; u < 4; ++u)
                    s = __builtin_amdgcn_fdot2(wp[u], mp[u], s, false);
            }
            float ch = tanhfast(s);
            float f  = f_ld[tid];
            float cc = f * c_ld[tid] + (1.0f - f) * ch;
            c_ld[tid] = cc;
            float h  = o_ld[tid] * tanhfast(cc);
            h_ld[tid] = h;
            orow[t * UU + tid] = h;
        }
        __syncthreads();
    }
}

// =====================================================================
extern "C" void kernel_launch(void* const* d_in, const int* in_sizes, int n_in,
                              void* d_out, int out_size, void* d_ws, size_t ws_size,
                              hipStream_t stream)
{
    (void)in_sizes; (void)n_in; (void)out_size;
    const float* x   = (const float*)d_in[0];
    const float* h0  = (const float*)d_in[1];
    const float* c0  = (const float*)d_in[2];
    const float* Wfs = (const float*)d_in[3];
    const float* bfs = (const float*)d_in[4];
    const float* Wfl = (const float*)d_in[5];
    const float* bfl = (const float*)d_in[6];
    const float* Wal = (const float*)d_in[7];
    const float* bal = (const float*)d_in[8];
    const float* Wm  = (const float*)d_in[9];
    const float* bm  = (const float*)d_in[10];
    const float* WC  = (const float*)d_in[11];
    const float* bC  = (const float*)d_in[12];
    const float* Wo  = (const float*)d_in[13];
    const float* bo  = (const float*)d_in[14];

    char* ws = (char*)d_ws;
    _Float16* W1   = (_Float16*)(ws + OFF_W1);
    _Float16* W2   = (_Float16*)(ws + OFF_W2);
    _Float16* WxT  = (_Float16*)(ws + OFF_WX);
    float*    b1   = (float*)   (ws + OFF_B1);
    u64*      hbT  = (u64*)     (ws + OFF_HB);
    u64*      mxT  = (u64*)     (ws + OFF_MX);
    _Float16* Xpre = (_Float16*)(ws + OFF_XPRE);

    repack_kernel<<<dim3(1024), dim3(256), 0, stream>>>(
        Wfs, Wfl, Wal, Wm, WC, Wo, bfs, bfl, bal, bm, bC, bo, W1, W2, WxT, b1, hbT);

    if (ws_size >= WS_FULL) {
        xpre_kernel<<<dim3(256, 18), dim3(256), 0, stream>>>(x, WxT, Xpre);
        rnn_coop<<<dim3(NBLK), dim3(256), 0, stream>>>(
            x, h0, c0, W1, W2, b1, Xpre, hbT, mxT, (float*)d_out);
    } else {
        rnn_fb<<<dim3(BB), dim3(704), 0, stream>>>(
            x, h0, c0, W1, W2, WxT, b1, (float*)d_out);
    }
}

// Round 3
// 6406.452 us; speedup vs baseline: 1.8635x; 1.8635x over previous
//
#include <hip/hip_runtime.h>
#include <hip/hip_fp16.h>
#include <math.h>

typedef _Float16 h2 __attribute__((ext_vector_type(2)));
typedef _Float16 h8 __attribute__((ext_vector_type(8)));
typedef float    f4 __attribute__((ext_vector_type(4)));
typedef unsigned int u4 __attribute__((ext_vector_type(4)));
typedef unsigned short     u16;
typedef unsigned int       u32;
typedef unsigned long long u64;

#define BB 64
#define TT 512
#define DD 256
#define UU 512

#define NBLK 64
#define CPB  44   // packed gate-cols per block: 8*{fs,fl,al,o,WCh} + 4 m
#define XPB  36   // of those, cols with an x-contribution (32 gate + 4 m)
#define UPB  8    // h/c columns owned per block
#define MPB  4    // m (x-dim) columns owned per block
#define NJ   2816
#define NJX  2304

// ---------- ws layout (bytes) ----------
#define OFF_W1   0ull                              // f16 [2816][512] packed, K-contig
#define OFF_W2   (OFF_W1 + 2816ull*512*2)          // f16 [512][256]
#define OFF_WX   (OFF_W2 + 512ull*256*2)           // f16 [2304][256] packed
#define OFF_B1   (OFF_WX + 2304ull*256*2)          // f32 [2816] packed
#define OFF_HB   (OFF_B1 + 2816ull*4)              // u64 [64][256] tagged h records
#define OFF_MX   (OFF_HB + 64ull*256*8)            // u64 [64][128] tagged mod_x records
#define OFF_CTR  (OFF_MX + 64ull*128*8)            // (legacy slot, unused)
#define OFF_XPRE (OFF_CTR + 16400ull*4)            // f16 [512][2304][64]
#define WS_FULL  (OFF_XPRE + 512ull*2304*64*2)     // ~155.7 MB

__device__ __forceinline__ float sigf(float v)     { return 1.0f / (1.0f + __expf(-v)); }
__device__ __forceinline__ float tanhfast(float v) { return 1.0f - 2.0f / (__expf(2.0f * v) + 1.0f); }

// [2 x f16 payload | u32 tag] in one single-copy-atomic u64
__device__ __forceinline__ u64 pack_rec(float a, float b, u32 tag) {
    _Float16 ha = (_Float16)a, hb = (_Float16)b;
    u16 ua, ub;
    __builtin_memcpy(&ua, &ha, 2);
    __builtin_memcpy(&ub, &hb, 2);
    return (u64)((u32)ua | ((u32)ub << 16)) | ((u64)tag << 32);
}

// packed-order helpers (fallback path)
__device__ __forceinline__ int pk5(int g, int u) { return (u >> 3) * 44 + g * 8 + (u & 7); }
__device__ __forceinline__ int pkm(int d)        { return (d >> 2) * 44 + 40 + (d & 3); }

// =====================================================================
// Kernel 1: repack weights into packed block-sliced f16 layouts + zero
// the tagged record buffers (tags from a previous launch would alias).
// =====================================================================
__global__ void repack_kernel(const float* __restrict__ Wfs, const float* __restrict__ Wfl,
                              const float* __restrict__ Wal, const float* __restrict__ Wm,
                              const float* __restrict__ WC,  const float* __restrict__ Wo,
                              const float* __restrict__ bfs, const float* __restrict__ bfl,
                              const float* __restrict__ bal, const float* __restrict__ bm,
                              const float* __restrict__ bC,  const float* __restrict__ bo,
                              _Float16* __restrict__ W1, _Float16* __restrict__ W2,
                              _Float16* __restrict__ WxT, float* __restrict__ b1,
                              u64* __restrict__ recs)
{
    const int stride = gridDim.x * blockDim.x;
    const int idx = blockIdx.x * blockDim.x + threadIdx.x;

    for (int i = idx; i < 2816 * 512; i += stride) {
        int J = i >> 9, k = i & 511;
        int blk = J / 44, c = J - blk * 44;
        float v;
        if (c < 40) {
            int grp = c >> 3, u = blk * 8 + (c & 7);
            const float* Wg = (grp == 0) ? Wfs : (grp == 1) ? Wfl : (grp == 2) ? Wal : (grp == 3) ? Wo : WC;
            v = Wg[(size_t)k * 512 + u];
        } else {
            int d = blk * 4 + (c - 40);
            v = Wm[(size_t)k * 256 + d];
        }
        W1[i] = (_Float16)v;
    }
    for (int i = idx; i < 512 * 256; i += stride) {
        int u = i >> 8, dd = i & 255;
        W2[i] = (_Float16)WC[(size_t)(512 + dd) * 512 + u];
    }
    for (int i = idx; i < 2304 * 256; i += stride) {
        int Jx = i >> 8, k2 = i & 255;
        int blk = Jx / 36, lc = Jx - blk * 36;
        float v;
        if (lc < 32) {
            int grp = lc >> 3, u = blk * 8 + (lc & 7);
            const float* Wg = (grp == 0) ? Wfs : (grp == 1) ? Wfl : (grp == 2) ? Wal : Wo;
            v = Wg[(size_t)(512 + k2) * 512 + u];
        } else {
            int d = blk * 4 + (lc - 32);
            v = Wm[(size_t)(512 + k2) * 256 + d];
        }
        WxT[i] = (_Float16)v;
    }
    for (int J = idx; J < 2816; J += stride) {
        int blk = J / 44, c = J - blk * 44;
        float v;
        if (c < 40) {
            int grp = c >> 3, u = blk * 8 + (c & 7);
            v = (grp == 0) ? bfs[u] : (grp == 1) ? bfl[u] : (grp == 2) ? bal[u] : (grp == 3) ? bo[u] : bC[u];
        } else {
            v = bm[blk * 4 + (c - 40)];
        }
        b1[J] = v;
    }
    // zero tagged h (64*256) + mx (64*128) records: 24576 u64
    for (int i = idx; i < 24576; i += stride) recs[i] = 0ull;
}

// =====================================================================
// Kernel 2: Xpre = x @ W_x via MFMA.  [32768,256]@[256,2304] -> f16
// output layout [t][Jx][b].
// =====================================================================
__global__ __launch_bounds__(256) void xpre_kernel(const float* __restrict__ x,
                                                   const _Float16* __restrict__ WxT,
                                                   _Float16* __restrict__ Xpre)
{
    __shared__ _Float16 As[128 * 32];
    __shared__ _Float16 Bs[128 * 32];

    const int tid  = threadIdx.x;
    const int lane = tid & 63;
    const int w    = tid >> 6;
    const int wm   = w >> 1, wn = w & 1;
    const int quad = lane >> 4, l16 = lane & 15;
    const int row0 = blockIdx.x * 128;
    const int n0   = blockIdx.y * 128;

    f4 acc[4][4];
    for (int i = 0; i < 4; ++i)
        for (int j = 0; j < 4; ++j)
            acc[i][j] = (f4){0.f, 0.f, 0.f, 0.f};

    for (int kt = 0; kt < 8; ++kt) {
        const int k0 = kt * 32;
        {
            int r  = tid >> 3;
            int cg = (tid & 7) * 4;
            for (int rr = r; rr < 128; rr += 32) {
                f4 v = *(const f4*)&x[(size_t)(row0 + rr) * 256 + k0 + cg];
                As[rr * 32 + cg + 0] = (_Float16)v.x;
                As[rr * 32 + cg + 1] = (_Float16)v.y;
                As[rr * 32 + cg + 2] = (_Float16)v.z;
                As[rr * 32 + cg + 3] = (_Float16)v.w;
            }
        }
        {
            int r   = tid & 127;
            int seg = (tid >> 7) * 16;
            const _Float16* src = &WxT[(size_t)(n0 + r) * 256 + k0 + seg];
            *(f4*)&Bs[r * 32 + seg]     = *(const f4*)src;
            *(f4*)&Bs[r * 32 + seg + 8] = *(const f4*)(src + 8);
        }
        __syncthreads();

        h8 af[4], bfr[4];
#pragma unroll
        for (int f = 0; f < 4; ++f) {
            af[f]  = *(const h8*)&As[(wm * 64 + f * 16 + l16) * 32 + quad * 8];
            bfr[f] = *(const h8*)&Bs[(wn * 64 + f * 16 + l16) * 32 + quad * 8];
        }
#pragma unroll
        for (int fm = 0; fm < 4; ++fm)
#pragma unroll
            for (int fn = 0; fn < 4; ++fn)
                acc[fm][fn] = __builtin_amdgcn_mfma_f32_16x16x32_f16(af[fm], bfr[fn], acc[fm][fn], 0, 0, 0);
        __syncthreads();
    }

#pragma unroll
    for (int fm = 0; fm < 4; ++fm)
#pragma unroll
        for (int fn = 0; fn < 4; ++fn)
#pragma unroll
            for (int r = 0; r < 4; ++r) {
                int rr = row0 + wm * 64 + fm * 16 + quad * 4 + r;  // x row = b*T+t
                int J  = n0 + wn * 64 + fn * 16 + l16;
                int b = rr >> 9, tt = rr & 511;
                Xpre[((size_t)tt * NJX + J) * 64 + b] = (_Float16)acc[fm][fn][r];
            }
}

// =====================================================================
// Kernel 3: cooperative recurrent scan, tagged records + CACHED
// coalesced poll-gather. 64 blocks x 256 thr. Per step:
//   retry { waitcnt; buffer_inv sc1; 32x b128 cached loads of own h
//   records; validate 64 tags in regs } -> bf frags -> acc2 -> quad2
//   publishes mod_x records (fire-and-forget, no drain, no flag) ->
//   acc0/acc1 -> barrier -> elementwise -> barrier -> retry-gather of
//   mx records (16x b128) -> GEMM2 -> update -> publish h records
//   (tag t+2, fire-and-forget) -> out store -> loop. 2 barriers/step,
//   zero producer-side serialization, detection==data (1 RTT/retry).
// Overwrite safety (as R2, which passed): A can't publish h(t+1)
// before consuming mx(t+1) from B, which requires B to have finished
// gathering h(t) — the recurrence's own deps double-buffer the records.
// =====================================================================
__global__ __launch_bounds__(256, 1) void rnn_coop(
    const float* __restrict__ x, const float* __restrict__ h0, const float* __restrict__ c0,
    const _Float16* __restrict__ W1, const _Float16* __restrict__ W2,
    const float* __restrict__ b1, const _Float16* __restrict__ Xpre,
    u64* __restrict__ hbufT, u64* __restrict__ mxbufT,
    float* __restrict__ out)
{
    __shared__ __align__(16) _Float16 sW1[48 * 512];  // 48 KB, resident all steps
    __shared__ float sS[48 * 68];                     // stride 68: 2-way max (free)
    __shared__ float sF[8 * 64];
    __shared__ float sO[8 * 64];
    __shared__ float sCP[8 * 64];
    __shared__ float sC[8 * 64];
    __shared__ float sB1[44];

    const int tid  = threadIdx.x;
    const int blk  = blockIdx.x;
    const int lane = tid & 63;
    const int w    = tid >> 6;
    const int l16  = lane & 15;
    const int quad = lane >> 4;
    const int swz  = l16 & 7;
    const int br   = w * 16 + l16;   // batch row owned in MFMA B-frags

    // ---- stage W1 slice (44 rows + 4 zero-pad) with chunk swizzle ----
    for (int idx = tid; idx < 48 * 64; idx += 256) {
        int r = idx >> 6, j = idx & 63;
        h8 v = {};
        if (r < CPB) v = *(const h8*)(W1 + ((size_t)(blk * CPB + r) * 512 + j * 8));
        *(h8*)&sW1[(r * 64 + (j ^ (r & 7))) * 8] = v;
    }
    // ---- W2 A-frags in registers for all steps (rows u<8, pad to 16) ----
    h8 af2[8];
#pragma unroll
    for (int ks = 0; ks < 8; ++ks) {
        af2[ks] = (h8){};
        if (l16 < 8)
            af2[ks] = *(const h8*)(W2 + (size_t)(blk * UPB + l16) * 256 + ks * 32 + quad * 8);
    }
    if (tid < CPB) sB1[tid] = b1[blk * CPB + tid];
    // ---- init c (block-local) ----
    for (int idx = tid; idx < UPB * 64; idx += 256) {
        int u = idx >> 6, b = idx & 63;
        sC[u * 64 + b] = c0[b * UU + blk * UPB + u];
    }
    // ---- publish our h0 slice as tagged records (tag 1), no drain ----
    if (tid < 128) {
        int q = tid >> 6, b = tid & 63;
        float v0 = h0[b * UU + blk * UPB + q * 4 + 0];
        float v1 = h0[b * UU + blk * UPB + q * 4 + 1];
        float v2 = h0[b * UU + blk * UPB + q * 4 + 2];
        float v3 = h0[b * UU + blk * UPB + q * 4 + 3];
        __hip_atomic_store(hbufT + (size_t)b * 256 + blk * 4 + q * 2 + 0, pack_rec(v0, v1, 1u),
                           __ATOMIC_RELAXED, __HIP_MEMORY_SCOPE_AGENT);
        __hip_atomic_store(hbufT + (size_t)b * 256 + blk * 4 + q * 2 + 1, pack_rec(v2, v3, 1u),
                           __ATOMIC_RELAXED, __HIP_MEMORY_SCOPE_AGENT);
    }
    __syncthreads();                      // LDS init (sW1, sB1, sC) ready

    for (int t = 0; t < TT; ++t) {
        // ---- prefetch read-only operands (overlap the gather) ----
        const _Float16* xp = Xpre + ((size_t)t * NJX + blk * XPB) * 64;
        float pfs[2], pfl[2], pal[2], pov[2];
#pragma unroll
        for (int i = 0; i < 2; ++i) {
            int u = w * 2 + i;
            pfs[i] = (float)xp[(size_t)u * 64 + lane];
            pfl[i] = (float)xp[(size_t)(8 + u) * 64 + lane];
            pal[i] = (float)xp[(size_t)(16 + u) * 64 + lane];
            pov[i] = (float)xp[(size_t)(24 + u) * 64 + lane];
        }
        float pxm[4] = {0.f, 0.f, 0.f, 0.f};
        f4 pxv = {0.f, 0.f, 0.f, 0.f};
        if (quad == 2) {
#pragma unroll
            for (int r = 0; r < 4; ++r)
                pxm[r] = (float)xp[(size_t)(32 + r) * 64 + br];
            pxv = *(const f4*)&x[((size_t)br * TT + t) * DD + blk * MPB];
        }

        const u32 expt = (u32)t + 1u;

        // ---- fused wait+gather of h(t-1): cached coalesced poll ----
        // Each lane reads its own 512B (64 recs) via 32x b128; lanes of a
        // wave cover full 64B lines. Tags validated in regs; retry re-invs.
        h8 bf[16];
        {
            const u4* hT = (const u4*)(hbufT + (size_t)br * 256);
            u32 guard = 0;
            for (;;) {
                asm volatile("s_waitcnt vmcnt(0)" ::: "memory");
                asm volatile("buffer_inv sc1" ::: "memory");
                u32 bad = 0;
#pragma unroll
                for (int ks = 0; ks < 16; ++ks) {
                    const int rb = (ks * 4 + quad) * 2;   // in u4 units (2 recs each)
                    u4 v0 = hT[rb];
                    u4 v1 = hT[rb + 1];
                    bad |= (v0.y ^ expt) | (v0.w ^ expt) | (v1.y ^ expt) | (v1.w ^ expt);
                    u32 d[4] = {v0.x, v0.z, v1.x, v1.z};
                    __builtin_memcpy(&bf[ks], d, 16);
                }
                if (__all(bad == 0)) break;
                if ((++guard & 63u) == 0u) {   // safety: known-good inv path
                    (void)__hip_atomic_load(hbufT, __ATOMIC_ACQUIRE, __HIP_MEMORY_SCOPE_AGENT);
                    if (guard > 500000u) break;
                }
            }
        }

        // ---- acc2 first: cols 32..47 = WCh(32..39) + m(40..43) ----
        f4 acc2 = {0.f, 0.f, 0.f, 0.f};
#pragma unroll
        for (int ks = 0; ks < 16; ++ks) {
            int jx = (ks * 4 + quad) ^ swz;
            h8 a2 = *(const h8*)&sW1[((32 + l16) * 64 + jx) * 8];
            acc2 = __builtin_amdgcn_mfma_f32_16x16x32_f16(a2, bf[ks], acc2, 0, 0, 0);
        }
        // WCh rows 32..39 to LDS (read at elementwise, after barrier B)
        if (quad < 2) {
#pragma unroll
            for (int r = 0; r < 4; ++r)
                sS[(32 + quad * 4 + r) * 68 + br] = acc2[r];
        }
        // mod_x straight from registers: quad2 lane holds preact[d=blk*4+r][br].
        // Publish as tagged records — fire-and-forget, no drain, no flag.
        if (quad == 2) {
#pragma unroll
            for (int p = 0; p < 2; ++p) {
                float m0 = sigf(acc2[2 * p]     + sB1[40 + 2 * p]     + pxm[2 * p])     * pxv[2 * p];
                float m1 = sigf(acc2[2 * p + 1] + sB1[40 + 2 * p + 1] + pxm[2 * p + 1]) * pxv[2 * p + 1];
                __hip_atomic_store(mxbufT + (size_t)br * 128 + blk * 2 + p, pack_rec(m0, m1, expt),
                                   __ATOMIC_RELAXED, __HIP_MEMORY_SCOPE_AGENT);
            }
        }

        // ---- acc0/acc1: cols 0..31 (fs,fl,al,o), reuse bf regs ----
        f4 acc0 = {0.f, 0.f, 0.f, 0.f}, acc1 = {0.f, 0.f, 0.f, 0.f};
#pragma unroll
        for (int ks = 0; ks < 16; ++ks) {
            int jx = (ks * 4 + quad) ^ swz;
            h8 a0 = *(const h8*)&sW1[((     l16) * 64 + jx) * 8];
            h8 a1 = *(const h8*)&sW1[((16 + l16) * 64 + jx) * 8];
            acc0 = __builtin_amdgcn_mfma_f32_16x16x32_f16(a0, bf[ks], acc0, 0, 0, 0);
            acc1 = __builtin_amdgcn_mfma_f32_16x16x32_f16(a1, bf[ks], acc1, 0, 0, 0);
        }
#pragma unroll
        for (int r = 0; r < 4; ++r) {
            sS[(     quad * 4 + r) * 68 + br] = acc0[r];
            sS[(16 + quad * 4 + r) * 68 + br] = acc1[r];
        }
        __syncthreads();                  // B: sS ready for cross-wave reads

        // ---- elementwise: f/o gates + cpre ----
#pragma unroll
        for (int i = 0; i < 2; ++i) {
            int u = w * 2 + i;
            float fs = sigf(sS[u * 68 + lane]        + sB1[u]      + pfs[i]);
            float fl = sigf(sS[(8 + u) * 68 + lane]  + sB1[8 + u]  + pfl[i]);
            float al = sigf(sS[(16 + u) * 68 + lane] + sB1[16 + u] + pal[i]);
            sF[u * 64 + lane]  = al * fs + (1.0f - al) * fl;
            sO[u * 64 + lane]  = sigf(sS[(24 + u) * 68 + lane] + sB1[24 + u] + pov[i]);
            sCP[u * 64 + lane] = sS[(32 + u) * 68 + lane] + sB1[32 + u];
        }
        __syncthreads();                  // C: sF/sO/sCP ready

        // ---- fused wait+gather of mod_x: cached coalesced poll ----
        h8 bf2[8];
        {
            const u4* mT = (const u4*)(mxbufT + (size_t)br * 128);
            u32 guard = 0;
            for (;;) {
                asm volatile("s_waitcnt vmcnt(0)" ::: "memory");
                asm volatile("buffer_inv sc1" ::: "memory");
                u32 bad = 0;
#pragma unroll
                for (int ks = 0; ks < 8; ++ks) {
                    const int rb = (ks * 4 + quad) * 2;
                    u4 v0 = mT[rb];
                    u4 v1 = mT[rb + 1];
                    bad |= (v0.y ^ expt) | (v0.w ^ expt) | (v1.y ^ expt) | (v1.w ^ expt);
                    u32 d[4] = {v0.x, v0.z, v1.x, v1.z};
                    __builtin_memcpy(&bf2[ks], d, 16);
                }
                if (__all(bad == 0)) break;
                if ((++guard & 63u) == 0u) {
                    (void)__hip_atomic_load(mxbufT, __ATOMIC_ACQUIRE, __HIP_MEMORY_SCOPE_AGENT);
                    if (guard > 500000u) break;
                }
            }
        }

        // ---- GEMM2: W2(regs) x mod_x(regs); update; publish h ----
        {
            f4 aq = {0.f, 0.f, 0.f, 0.f};
#pragma unroll
            for (int ks = 0; ks < 8; ++ks)
                aq = __builtin_amdgcn_mfma_f32_16x16x32_f16(af2[ks], bf2[ks], aq, 0, 0, 0);

            if (quad < 2) {
                const int u0 = quad * 4;
                float hv[4];
#pragma unroll
                for (int r = 0; r < 4; ++r) {
                    int u = u0 + r;
                    float ch = tanhfast(aq[r] + sCP[u * 64 + br]);
                    float f  = sF[u * 64 + br];
                    float c  = f * sC[u * 64 + br] + (1.0f - f) * ch;
                    sC[u * 64 + br] = c;
                    hv[r] = sO[u * 64 + br] * tanhfast(c);
                }
                const u32 tagh = (u32)t + 2u;
                __hip_atomic_store(hbufT + (size_t)br * 256 + blk * 4 + quad * 2 + 0,
                                   pack_rec(hv[0], hv[1], tagh),
                                   __ATOMIC_RELAXED, __HIP_MEMORY_SCOPE_AGENT);
                __hip_atomic_store(hbufT + (size_t)br * 256 + blk * 4 + quad * 2 + 1,
                                   pack_rec(hv[2], hv[3], tagh),
                                   __ATOMIC_RELAXED, __HIP_MEMORY_SCOPE_AGENT);
                f4 ovec = {hv[0], hv[1], hv[2], hv[3]};
                __builtin_nontemporal_store(ovec, (f4*)&out[((size_t)br * TT + t) * UU + blk * UPB + u0]);
            }
        }
        // no end-of-step barrier: the next h-gather can only pass once all
        // blocks (and this block's sibling waves) have published h(t),
        // which transitively orders all LDS reuse.
    }
}

// =====================================================================
// Fallback (small ws): per-batch dot2 scan on packed weights.
// =====================================================================
__global__ __launch_bounds__(704) void rnn_fb(const float* __restrict__ x,
                                              const float* __restrict__ h0,
                                              const float* __restrict__ c0,
                                              const _Float16* __restrict__ W1,
                                              const _Float16* __restrict__ W2,
                                              const _Float16* __restrict__ WxT,
                                              const float* __restrict__ b1g,
                                              float* __restrict__ out)
{
    __shared__ float g_ld[2816];
    __shared__ float b1_ld[2816];
    __shared__ float h_ld[512];
    __shared__ float x_ld[256];
    __shared__ float f_ld[512];
    __shared__ float o_ld[512];
    __shared__ float c_ld[512];
    __shared__ __align__(16) h2 hx_h2[256];
    __shared__ __align__(16) h2 x16_h2[128];
    __shared__ __align__(16) h2 modx_h2[128];

    const int tid = threadIdx.x;
    const int b   = blockIdx.x;
    const int j0  = tid * 4;
    const int c   = j0 % 44;
    const bool hasx = (c < 32) || (c >= 40);
    const int Jx0 = (j0 / 44) * 36 + (c < 32 ? c : c - 8);

    for (int j = tid; j < 2816; j += 704) b1_ld[j] = b1g[j];
    if (tid < 512) {
        h_ld[tid] = h0[b * 512 + tid];
        c_ld[tid] = c0[b * 512 + tid];
    }
    __syncthreads();

    const f4* __restrict__ w1r = (const f4*)(W1 + (size_t)j0 * 512);
    const float* __restrict__ xrow = x + (size_t)b * TT * DD;
    float* __restrict__ orow = out + (size_t)b * TT * UU;

    for (int t = 0; t < TT; ++t) {
        if (tid < 256) {
            h2 p; p[0] = (_Float16)h_ld[2 * tid]; p[1] = (_Float16)h_ld[2 * tid + 1];
            hx_h2[tid] = p;
        } else if (tid < 384) {
            int i = tid - 256;
            float v0 = xrow[t * DD + 2 * i];
            float v1 = xrow[t * DD + 2 * i + 1];
            x_ld[2 * i] = v0; x_ld[2 * i + 1] = v1;
            h2 p; p[0] = (_Float16)v0; p[1] = (_Float16)v1;
            x16_h2[i] = p;
        }
        __syncthreads();

        float a0 = b1_ld[j0], a1 = b1_ld[j0 + 1], a2 = b1_ld[j0 + 2], a3 = b1_ld[j0 + 3];
        if (hasx) {
            const f4* xr0 = (const f4*)(WxT + (size_t)Jx0 * 256);
            const f4* xr1 = xr0 + 32;
            const f4* xr2 = xr0 + 64;
            const f4* xr3 = xr0 + 96;
            const f4* xv4 = (const f4*)x16_h2;
#pragma unroll 4
            for (int kc = 0; kc < 32; ++kc) {
                f4 xv = xv4[kc];
                f4 w0 = xr0[kc], w1 = xr1[kc], w2 = xr2[kc], w3 = xr3[kc];
                const h2* xpv = (const h2*)&xv;
                const h2* p0 = (const h2*)&w0; const h2* p1 = (const h2*)&w1;
                const h2* p2 = (const h2*)&w2; const h2* p3 = (const h2*)&w3;
#pragma unroll
                for (int u = 0; u < 4; ++u) {
                    a0 = __builtin_amdgcn_fdot2(p0[u], xpv[u], a0, false);
                    a1 = __builtin_amdgcn_fdot2(p1[u], xpv[u], a1, false);
                    a2 = __builtin_amdgcn_fdot2(p2[u], xpv[u], a2, false);
                    a3 = __builtin_amdgcn_fdot2(p3[u], xpv[u], a3, false);
                }
            }
        }
        {
            const f4* hx4 = (const f4*)hx_h2;
            const f4* r0 = w1r;
            const f4* r1 = w1r + 64;
            const f4* r2 = w1r + 128;
            const f4* r3 = w1r + 192;
#pragma unroll 4
            for (int kc = 0; kc < 64; ++kc) {
                f4 hv = hx4[kc];
                f4 w0 = r0[kc], w1 = r1[kc], w2 = r2[kc], w3 = r3[kc];
                const h2* hp = (const h2*)&hv;
                const h2* p0 = (const h2*)&w0; const h2* p1 = (const h2*)&w1;
                const h2* p2 = (const h2*)&w2; const h2* p3 = (const h2*)&w3;
#pragma unroll
                for (int u = 0; u < 4; ++u) {
                    a0 = __builtin_amdgcn_fdot2(p0[u], hp[u], a0, false);
                    a1 = __builtin_amdgcn_fdot2(p1[u], hp[u], a1, false);
                    a2 = __builtin_amdgcn_fdot2(p2[u], hp[u], a2, false);
                    a3 = __builtin_amdgcn_fdot2(p3[u], hp[u], a3, false);
                }
            }
        }
        g_ld[j0] = a0; g_ld[j0 + 1] = a1; g_ld[j0 + 2] = a2; g_ld[j0 + 3] = a3;
        __syncthreads();

        if (tid < 128) {
            float m0 = sigf(g_ld[pkm(2 * tid)]);
            float m1 = sigf(g_ld[pkm(2 * tid + 1)]);
            h2 p;
            p[0] = (_Float16)(m0 * x_ld[2 * tid]);
            p[1] = (_Float16)(m1 * x_ld[2 * tid + 1]);
            modx_h2[tid] = p;
        } else if (tid < 640) {
            int u = tid - 128;
            float fs = sigf(g_ld[pk5(0, u)]);
            float fl = sigf(g_ld[pk5(1, u)]);
            float al = sigf(g_ld[pk5(2, u)]);
            f_ld[u] = al * fs + (1.0f - al) * fl;
            o_ld[u] = sigf(g_ld[pk5(3, u)]);
        }
        __syncthreads();

        if (tid < 512) {
            float s = g_ld[pk5(4, tid)];
            const f4* w2r = (const f4*)(W2 + (size_t)tid * 256);
            const f4* mx4 = (const f4*)modx_h2;
#pragma unroll 4
            for (int kc = 0; kc < 32; ++kc) {
                f4 wv = w2r[kc];
                f4 mv = mx4[kc];
                const h2* wp = (const h2*)&wv;
                const h2* mp = (const h2*)&mv;
#pragma unroll
                for (int u = 0; u < 4; ++u)
                    s = __builtin_amdgcn_fdot2(wp[u], mp[u], s, false);
            }
            float ch = tanhfast(s);
            float f  = f_ld[tid];
            float cc = f * c_ld[tid] + (1.0f - f) * ch;
            c_ld[tid] = cc;
            float h  = o_ld[tid] * tanhfast(cc);
            h_ld[tid] = h;
            orow[t * UU + tid] = h;
        }
        __syncthreads();
    }
}

// =====================================================================
extern "C" void kernel_launch(void* const* d_in, const int* in_sizes, int n_in,
                              void* d_out, int out_size, void* d_ws, size_t ws_size,
                              hipStream_t stream)
{
    (void)in_sizes; (void)n_in; (void)out_size;
    const float* x   = (const float*)d_in[0];
    const float* h0  = (const float*)d_in[1];
    const float* c0  = (const float*)d_in[2];
    const float* Wfs = (const float*)d_in[3];
    const float* bfs = (const float*)d_in[4];
    const float* Wfl = (const float*)d_in[5];
    const float* bfl = (const float*)d_in[6];
    const float* Wal = (const float*)d_in[7];
    const float* bal = (const float*)d_in[8];
    const float* Wm  = (const float*)d_in[9];
    const float* bm  = (const float*)d_in[10];
    const float* WC  = (const float*)d_in[11];
    const float* bC  = (const float*)d_in[12];
    const float* Wo  = (const float*)d_in[13];
    const float* bo  = (const float*)d_in[14];

    char* ws = (char*)d_ws;
    _Float16* W1   = (_Float16*)(ws + OFF_W1);
    _Float16* W2   = (_Float16*)(ws + OFF_W2);
    _Float16* WxT  = (_Float16*)(ws + OFF_WX);
    float*    b1   = (float*)   (ws + OFF_B1);
    u64*      hbT  = (u64*)     (ws + OFF_HB);
    u64*      mxT  = (u64*)     (ws + OFF_MX);
    _Float16* Xpre = (_Float16*)(ws + OFF_XPRE);

    repack_kernel<<<dim3(1024), dim3(256), 0, stream>>>(
        Wfs, Wfl, Wal, Wm, WC, Wo, bfs, bfl, bal, bm, bC, bo, W1, W2, WxT, b1, hbT);

    if (ws_size >= WS_FULL) {
        xpre_kernel<<<dim3(256, 18), dim3(256), 0, stream>>>(x, WxT, Xpre);
        rnn_coop<<<dim3(NBLK), dim3(256), 0, stream>>>(
            x, h0, c0, W1, W2, b1, Xpre, hbT, mxT, (float*)d_out);
    } else {
        rnn_fb<<<dim3(BB), dim3(704), 0, stream>>>(
            x, h0, c0, W1, W2, WxT, b1, (float*)d_out);
    }
}

// Round 5
// 4484.888 us; speedup vs baseline: 2.6619x; 1.4285x over previous
//
#include <hip/hip_runtime.h>
#include <hip/hip_fp16.h>
#include <math.h>

typedef _Float16 h2 __attribute__((ext_vector_type(2)));
typedef _Float16 h8 __attribute__((ext_vector_type(8)));
typedef float    f4 __attribute__((ext_vector_type(4)));
typedef unsigned short     u16;
typedef unsigned int       u32;
typedef unsigned long long u64;

#define BB 64
#define TT 512
#define DD 256
#define UU 512

#define NBLK 64
#define CPB  44   // packed gate-cols per block: 8*{fs,fl,al,o,WCh} + 4 m
#define XPB  36   // of those, cols with an x-contribution (32 gate + 4 m)
#define UPB  8    // h/c columns owned per block
#define MPB  4    // m (x-dim) columns owned per block
#define NJ   2816
#define NJX  2304

// ---------- ws layout (bytes) ----------
#define OFF_W1   0ull                              // f16 [2816][512] packed, K-contig
#define OFF_W2   (OFF_W1 + 2816ull*512*2)          // f16 [512][256]
#define OFF_WX   (OFF_W2 + 512ull*256*2)           // f16 [2304][256] packed
#define OFF_B1   (OFF_WX + 2304ull*256*2)          // f32 [2816] packed
#define OFF_HB   (OFF_B1 + 2816ull*4)              // f16 [64][512]  h state
#define OFF_MX   (OFF_HB + 64ull*512*2)            // f16 [64][256]  mod_x
#define OFF_CTR  (OFF_MX + 64ull*256*2)            // u32 [16400] flag lines
#define OFF_XPRE (OFF_CTR + 16400ull*4)            // f16 [512][2304][64]
#define WS_FULL  (OFF_XPRE + 512ull*2304*64*2)     // ~155.5 MB

__device__ __forceinline__ float sigf(float v)     { return 1.0f / (1.0f + __expf(-v)); }
__device__ __forceinline__ float tanhfast(float v) { return 1.0f - 2.0f / (__expf(2.0f * v) + 1.0f); }

// Per-WAVE plane wait: lane j polls flag line j (64B apart) of this plane.
// Same proven R1 protocol (relaxed poll, ballot, one acquire->buffer_inv),
// but executed independently per wave so planes never couple.
__device__ __forceinline__ void plane_wait(u32* base, u32 tgt, int lane) {
    u32 it = 0;
    for (;;) {
        u32 v = __hip_atomic_load(base + lane * 16, __ATOMIC_RELAXED, __HIP_MEMORY_SCOPE_AGENT);
        if (__ballot(v >= tgt) == ~0ull) break;
        __builtin_amdgcn_s_sleep(1);
        if (++it > 4000000u) break;   // safety valve
    }
    (void)__hip_atomic_load(base + lane * 16, __ATOMIC_ACQUIRE, __HIP_MEMORY_SCOPE_AGENT);
}

// packed-order helpers (fallback path)
__device__ __forceinline__ int pk5(int g, int u) { return (u >> 3) * 44 + g * 8 + (u & 7); }
__device__ __forceinline__ int pkm(int d)        { return (d >> 2) * 44 + 40 + (d & 3); }

// =====================================================================
// Kernel 1: repack weights into packed block-sliced f16 layouts + zero flags
// =====================================================================
__global__ void repack_kernel(const float* __restrict__ Wfs, const float* __restrict__ Wfl,
                              const float* __restrict__ Wal, const float* __restrict__ Wm,
                              const float* __restrict__ WC,  const float* __restrict__ Wo,
                              const float* __restrict__ bfs, const float* __restrict__ bfl,
                              const float* __restrict__ bal, const float* __restrict__ bm,
                              const float* __restrict__ bC,  const float* __restrict__ bo,
                              _Float16* __restrict__ W1, _Float16* __restrict__ W2,
                              _Float16* __restrict__ WxT, float* __restrict__ b1,
                              u32* __restrict__ ctr)
{
    const int stride = gridDim.x * blockDim.x;
    const int idx = blockIdx.x * blockDim.x + threadIdx.x;

    for (int i = idx; i < 2816 * 512; i += stride) {
        int J = i >> 9, k = i & 511;
        int blk = J / 44, c = J - blk * 44;
        float v;
        if (c < 40) {
            int grp = c >> 3, u = blk * 8 + (c & 7);
            const float* Wg = (grp == 0) ? Wfs : (grp == 1) ? Wfl : (grp == 2) ? Wal : (grp == 3) ? Wo : WC;
            v = Wg[(size_t)k * 512 + u];
        } else {
            int d = blk * 4 + (c - 40);
            v = Wm[(size_t)k * 256 + d];
        }
        W1[i] = (_Float16)v;
    }
    for (int i = idx; i < 512 * 256; i += stride) {
        int u = i >> 8, dd = i & 255;
        W2[i] = (_Float16)WC[(size_t)(512 + dd) * 512 + u];
    }
    for (int i = idx; i < 2304 * 256; i += stride) {
        int Jx = i >> 8, k2 = i & 255;
        int blk = Jx / 36, lc = Jx - blk * 36;
        float v;
        if (lc < 32) {
            int grp = lc >> 3, u = blk * 8 + (lc & 7);
            const float* Wg = (grp == 0) ? Wfs : (grp == 1) ? Wfl : (grp == 2) ? Wal : Wo;
            v = Wg[(size_t)(512 + k2) * 512 + u];
        } else {
            int d = blk * 4 + (lc - 32);
            v = Wm[(size_t)(512 + k2) * 256 + d];
        }
        WxT[i] = (_Float16)v;
    }
    for (int J = idx; J < 2816; J += stride) {
        int blk = J / 44, c = J - blk * 44;
        float v;
        if (c < 40) {
            int grp = c >> 3, u = blk * 8 + (c & 7);
            v = (grp == 0) ? bfs[u] : (grp == 1) ? bfl[u] : (grp == 2) ? bal[u] : (grp == 3) ? bo[u] : bC[u];
        } else {
            v = bm[blk * 4 + (c - 40)];
        }
        b1[J] = v;
    }
    for (int i = idx; i < 16400; i += stride) ctr[i] = 0;
}

// =====================================================================
// Kernel 2: Xpre = x @ W_x via MFMA.  [32768,256]@[256,2304] -> f16
// output layout [t][Jx][b].
// =====================================================================
__global__ __launch_bounds__(256) void xpre_kernel(const float* __restrict__ x,
                                                   const _Float16* __restrict__ WxT,
                                                   _Float16* __restrict__ Xpre)
{
    __shared__ _Float16 As[128 * 32];
    __shared__ _Float16 Bs[128 * 32];

    const int tid  = threadIdx.x;
    const int lane = tid & 63;
    const int w    = tid >> 6;
    const int wm   = w >> 1, wn = w & 1;
    const int quad = lane >> 4, l16 = lane & 15;
    const int row0 = blockIdx.x * 128;
    const int n0   = blockIdx.y * 128;

    f4 acc[4][4];
    for (int i = 0; i < 4; ++i)
        for (int j = 0; j < 4; ++j)
            acc[i][j] = (f4){0.f, 0.f, 0.f, 0.f};

    for (int kt = 0; kt < 8; ++kt) {
        const int k0 = kt * 32;
        {
            int r  = tid >> 3;
            int cg = (tid & 7) * 4;
            for (int rr = r; rr < 128; rr += 32) {
                f4 v = *(const f4*)&x[(size_t)(row0 + rr) * 256 + k0 + cg];
                As[rr * 32 + cg + 0] = (_Float16)v.x;
                As[rr * 32 + cg + 1] = (_Float16)v.y;
                As[rr * 32 + cg + 2] = (_Float16)v.z;
                As[rr * 32 + cg + 3] = (_Float16)v.w;
            }
        }
        {
            int r   = tid & 127;
            int seg = (tid >> 7) * 16;
            const _Float16* src = &WxT[(size_t)(n0 + r) * 256 + k0 + seg];
            *(f4*)&Bs[r * 32 + seg]     = *(const f4*)src;
            *(f4*)&Bs[r * 32 + seg + 8] = *(const f4*)(src + 8);
        }
        __syncthreads();

        h8 af[4], bfr[4];
#pragma unroll
        for (int f = 0; f < 4; ++f) {
            af[f]  = *(const h8*)&As[(wm * 64 + f * 16 + l16) * 32 + quad * 8];
            bfr[f] = *(const h8*)&Bs[(wn * 64 + f * 16 + l16) * 32 + quad * 8];
        }
#pragma unroll
        for (int fm = 0; fm < 4; ++fm)
#pragma unroll
            for (int fn = 0; fn < 4; ++fn)
                acc[fm][fn] = __builtin_amdgcn_mfma_f32_16x16x32_f16(af[fm], bfr[fn], acc[fm][fn], 0, 0, 0);
        __syncthreads();
    }

#pragma unroll
    for (int fm = 0; fm < 4; ++fm)
#pragma unroll
        for (int fn = 0; fn < 4; ++fn)
#pragma unroll
            for (int r = 0; r < 4; ++r) {
                int rr = row0 + wm * 64 + fm * 16 + quad * 4 + r;  // x row = b*T+t
                int J  = n0 + wn * 64 + fn * 16 + l16;
                int b = rr >> 9, tt = rr & 511;
                Xpre[((size_t)tt * NJX + J) * 64 + b] = (_Float16)acc[fm][fn][r];
            }
}

// =====================================================================
// Kernel 3: cooperative scan with 4 INDEPENDENT wave-planes per block.
// 64 blocks x 256 thr. Wave q of every block owns batch rows 16q..16q+15
// end-to-end: its own h-flag plane, mx-flag plane, MFMA frags, register
// elementwise (2 shfl_xor per r), register c state, and publishes. ZERO
// block barriers in the loop; no sS/sF/sO/sCP/sC LDS. Planes phase-shift
// freely, so one plane's LLC waits overlap other planes' compute and
// block-wide jitter coupling vanishes.
// Flag lines: hflag[(q*64+blk)*16] holds step+1; mxflag at +4096.
// Overwrite safety per plane: identical recurrence-dependency argument to
// R1/R2 (h(t+1) publish requires mx(t) gather, which requires all h(t)
// gathers complete).
// =====================================================================
__global__ __launch_bounds__(256, 1) void rnn_coop(
    const float* __restrict__ x, const float* __restrict__ h0, const float* __restrict__ c0,
    const _Float16* __restrict__ W1, const _Float16* __restrict__ W2,
    const float* __restrict__ b1, const _Float16* __restrict__ Xpre,
    _Float16* __restrict__ hbuf, _Float16* __restrict__ mxbuf, u32* __restrict__ ctr,
    float* __restrict__ out)
{
    __shared__ __align__(16) _Float16 sW1[48 * 512];  // 48 KB, resident all steps
    __shared__ float sB1[44];

    const int tid  = threadIdx.x;
    const int blk  = blockIdx.x;
    const int lane = tid & 63;
    const int q    = tid >> 6;       // wave = batch-quarter plane
    const int l16  = lane & 15;
    const int quad = lane >> 4;
    const int swz  = l16 & 7;
    const int br   = q * 16 + l16;   // global batch row owned in MFMA frags

    // ---- stage W1 slice (44 rows + 4 zero-pad) with chunk swizzle ----
    for (int idx = tid; idx < 48 * 64; idx += 256) {
        int r = idx >> 6, j = idx & 63;
        h8 v = {};
        if (r < CPB) v = *(const h8*)(W1 + ((size_t)(blk * CPB + r) * 512 + j * 8));
        *(h8*)&sW1[(r * 64 + (j ^ (r & 7))) * 8] = v;
    }
    // ---- W2 A-frags in registers (rows u<8 via l16, pad to 16) ----
    h8 af2[8];
#pragma unroll
    for (int ks = 0; ks < 8; ++ks) {
        af2[ks] = (h8){};
        if (l16 < 8)
            af2[ks] = *(const h8*)(W2 + (size_t)(blk * UPB + l16) * 256 + ks * 32 + quad * 8);
    }
    if (tid < CPB) sB1[tid] = b1[blk * CPB + tid];
    // ---- c state in registers: quad<2 lane holds c[u=quad*4+r][b=br] ----
    float cr[4] = {0.f, 0.f, 0.f, 0.f};
    if (quad < 2) {
#pragma unroll
        for (int r = 0; r < 4; ++r)
            cr[r] = c0[(size_t)br * UU + blk * UPB + quad * 4 + r];
    }
    // ---- publish our h0 slice (all 64 b x our 8 u) ----
    if (tid < 128) {
        int qq = tid >> 6, b = tid & 63;
        _Float16 hp[4];
#pragma unroll
        for (int r = 0; r < 4; ++r) hp[r] = (_Float16)h0[(size_t)b * UU + blk * UPB + qq * 4 + r];
        u64 hq; __builtin_memcpy(&hq, hp, 8);
        __hip_atomic_store((u64*)(hbuf + (size_t)b * 512 + blk * UPB + qq * 4), hq,
                           __ATOMIC_RELAXED, __HIP_MEMORY_SCOPE_AGENT);
    }
    __syncthreads();                      // LDS init + all waves' h0 stores drained
    if (tid < 4)
        __hip_atomic_store(&ctr[(tid * 64 + blk) * 16], 1u,
                           __ATOMIC_RELAXED, __HIP_MEMORY_SCOPE_AGENT);

    u32* hfl = ctr + (size_t)q * 1024;          // lane j polls +j*16
    u32* mfl = ctr + 4096 + (size_t)q * 1024;

    for (int t = 0; t < TT; ++t) {
        // ---- prefetch read-only operands (overlap the plane wait) ----
        float pfs[4], pflv[4], pal[4], pov[4];
        float pxm[4] = {0.f, 0.f, 0.f, 0.f};
        f4 pxv = {0.f, 0.f, 0.f, 0.f};
        if (quad < 2) {
            const _Float16* xp = Xpre + ((size_t)t * NJX + blk * XPB) * 64 + br;
#pragma unroll
            for (int r = 0; r < 4; ++r) {
                int u = quad * 4 + r;
                pfs[r]  = (float)xp[(size_t)u * 64];
                pflv[r] = (float)xp[(size_t)(8 + u) * 64];
                pal[r]  = (float)xp[(size_t)(16 + u) * 64];
                pov[r]  = (float)xp[(size_t)(24 + u) * 64];
            }
        } else if (quad == 2) {
            const _Float16* xq = Xpre + ((size_t)t * NJX + blk * XPB + 32) * 64 + br;
#pragma unroll
            for (int r = 0; r < 4; ++r) pxm[r] = (float)xq[(size_t)r * 64];
            pxv = *(const f4*)&x[((size_t)br * TT + t) * DD + blk * MPB];
        }

        // ---- wait h(t-1), own plane only ----
        plane_wait(hfl, (u32)t + 1u, lane);

        // ---- B-frags: h[br][*] straight from cache into registers ----
        h8 bf[16];
#pragma unroll
        for (int ks = 0; ks < 16; ++ks)
            bf[ks] = *(const h8*)(hbuf + (size_t)br * 512 + (ks * 4 + quad) * 8);

        // ---- acc2: rows 32..47 = WCh(32..39) + m(40..43) ----
        f4 acc2 = {0.f, 0.f, 0.f, 0.f};
#pragma unroll
        for (int ks = 0; ks < 16; ++ks) {
            int jx = (ks * 4 + quad) ^ swz;
            h8 a2 = *(const h8*)&sW1[((32 + l16) * 64 + jx) * 8];
            acc2 = __builtin_amdgcn_mfma_f32_16x16x32_f16(a2, bf[ks], acc2, 0, 0, 0);
        }
        // mod_x from regs: quad2 lane holds preact[d=blk*4+r][br]
        if (quad == 2) {
            _Float16 mp[4];
#pragma unroll
            for (int r = 0; r < 4; ++r) {
                float mr = acc2[r] + sB1[40 + r] + pxm[r];
                mp[r] = (_Float16)(sigf(mr) * pxv[r]);
            }
            u64 mq; __builtin_memcpy(&mq, mp, 8);
            __hip_atomic_store((u64*)(mxbuf + (size_t)br * 256 + blk * MPB), mq,
                               __ATOMIC_RELAXED, __HIP_MEMORY_SCOPE_AGENT);
        }

        // ---- acc0/acc1: rows 0..31; mx store drains underneath ----
        f4 acc0 = {0.f, 0.f, 0.f, 0.f}, acc1 = {0.f, 0.f, 0.f, 0.f};
#pragma unroll
        for (int ks = 0; ks < 16; ++ks) {
            int jx = (ks * 4 + quad) ^ swz;
            h8 a0 = *(const h8*)&sW1[((     l16) * 64 + jx) * 8];
            h8 a1 = *(const h8*)&sW1[((16 + l16) * 64 + jx) * 8];
            acc0 = __builtin_amdgcn_mfma_f32_16x16x32_f16(a0, bf[ks], acc0, 0, 0, 0);
            acc1 = __builtin_amdgcn_mfma_f32_16x16x32_f16(a1, bf[ks], acc1, 0, 0, 0);
        }
        asm volatile("s_waitcnt vmcnt(0)" ::: "memory");
        if (quad == 2 && l16 == 0)
            __hip_atomic_store(&mfl[blk * 16], (u32)t + 1u,
                               __ATOMIC_RELAXED, __HIP_MEMORY_SCOPE_AGENT);

        // ---- elementwise fully in registers (2 shfl per r) ----
        // lane map: quad0/1 hold rows u=quad*4+r of {fs,al,WCh}; quads 2/3
        // hold the matching {fl,o} rows — fetch via shfl_xor(32).
        float fv[4], ov[4], cpv[4];
#pragma unroll
        for (int r = 0; r < 4; ++r) {
            float flsh = __shfl_xor(acc0[r], 32);
            float osh  = __shfl_xor(acc1[r], 32);
            if (quad < 2) {
                int u = quad * 4 + r;
                float fs = sigf(acc0[r] + sB1[u]      + pfs[r]);
                float fl = sigf(flsh    + sB1[8 + u]  + pflv[r]);
                float al = sigf(acc1[r] + sB1[16 + u] + pal[r]);
                fv[r]  = al * fs + (1.0f - al) * fl;
                ov[r]  = sigf(osh + sB1[24 + u] + pov[r]);
                cpv[r] = acc2[r] + sB1[32 + u];
            }
        }

        // ---- wait mod_x, own plane only ----
        plane_wait(mfl, (u32)t + 1u, lane);

        // ---- GEMM2: W2(regs) x mod_x(cache) ----
        h8 bf2[8];
#pragma unroll
        for (int ks = 0; ks < 8; ++ks)
            bf2[ks] = *(const h8*)(mxbuf + (size_t)br * 256 + (ks * 4 + quad) * 8);
        f4 aq = {0.f, 0.f, 0.f, 0.f};
#pragma unroll
        for (int ks = 0; ks < 8; ++ks)
            aq = __builtin_amdgcn_mfma_f32_16x16x32_f16(af2[ks], bf2[ks], aq, 0, 0, 0);

        // ---- state update in regs; publish h; fire own plane flag ----
        f4 ovec = {0.f, 0.f, 0.f, 0.f};
        if (quad < 2) {
            float hv[4];
#pragma unroll
            for (int r = 0; r < 4; ++r) {
                float ch = tanhfast(aq[r] + cpv[r]);
                float f  = fv[r];
                float c  = f * cr[r] + (1.0f - f) * ch;
                cr[r] = c;
                hv[r] = ov[r] * tanhfast(c);
            }
            _Float16 hp[4] = {(_Float16)hv[0], (_Float16)hv[1], (_Float16)hv[2], (_Float16)hv[3]};
            u64 hq; __builtin_memcpy(&hq, hp, 8);
            __hip_atomic_store((u64*)(hbuf + (size_t)br * 512 + blk * UPB + quad * 4), hq,
                               __ATOMIC_RELAXED, __HIP_MEMORY_SCOPE_AGENT);
            ovec = (f4){hv[0], hv[1], hv[2], hv[3]};
        }
        asm volatile("s_waitcnt vmcnt(0)" ::: "memory");
        if (lane == 0)
            __hip_atomic_store(&hfl[blk * 16], (u32)t + 2u,
                               __ATOMIC_RELAXED, __HIP_MEMORY_SCOPE_AGENT);
        // out store AFTER the fire: HBM ack drains under next wait
        if (quad < 2)
            __builtin_nontemporal_store(ovec,
                (f4*)&out[((size_t)br * TT + t) * UU + blk * UPB + quad * 4]);
    }
}

// =====================================================================
// Fallback (small ws): per-batch dot2 scan on packed weights.
// =====================================================================
__global__ __launch_bounds__(704) void rnn_fb(const float* __restrict__ x,
                                              const float* __restrict__ h0,
                                              const float* __restrict__ c0,
                                              const _Float16* __restrict__ W1,
                                              const _Float16* __restrict__ W2,
                                              const _Float16* __restrict__ WxT,
                                              const float* __restrict__ b1g,
                                              float* __restrict__ out)
{
    __shared__ float g_ld[2816];
    __shared__ float b1_ld[2816];
    __shared__ float h_ld[512];
    __shared__ float x_ld[256];
    __shared__ float f_ld[512];
    __shared__ float o_ld[512];
    __shared__ float c_ld[512];
    __shared__ __align__(16) h2 hx_h2[256];
    __shared__ __align__(16) h2 x16_h2[128];
    __shared__ __align__(16) h2 modx_h2[128];

    const int tid = threadIdx.x;
    const int b   = blockIdx.x;
    const int j0  = tid * 4;
    const int c   = j0 % 44;
    const bool hasx = (c < 32) || (c >= 40);
    const int Jx0 = (j0 / 44) * 36 + (c < 32 ? c : c - 8);

    for (int j = tid; j < 2816; j += 704) b1_ld[j] = b1g[j];
    if (tid < 512) {
        h_ld[tid] = h0[b * 512 + tid];
        c_ld[tid] = c0[b * 512 + tid];
    }
    __syncthreads();

    const f4* __restrict__ w1r = (const f4*)(W1 + (size_t)j0 * 512);
    const float* __restrict__ xrow = x + (size_t)b * TT * DD;
    float* __restrict__ orow = out + (size_t)b * TT * UU;

    for (int t = 0; t < TT; ++t) {
        if (tid < 256) {
            h2 p; p[0] = (_Float16)h_ld[2 * tid]; p[1] = (_Float16)h_ld[2 * tid + 1];
            hx_h2[tid] = p;
        } else if (tid < 384) {
            int i = tid - 256;
            float v0 = xrow[t * DD + 2 * i];
            float v1 = xrow[t * DD + 2 * i + 1];
            x_ld[2 * i] = v0; x_ld[2 * i + 1] = v1;
            h2 p; p[0] = (_Float16)v0; p[1] = (_Float16)v1;
            x16_h2[i] = p;
        }
        __syncthreads();

        float a0 = b1_ld[j0], a1 = b1_ld[j0 + 1], a2 = b1_ld[j0 + 2], a3 = b1_ld[j0 + 3];
        if (hasx) {
            const f4* xr0 = (const f4*)(WxT + (size_t)Jx0 * 256);
            const f4* xr1 = xr0 + 32;
            const f4* xr2 = xr0 + 64;
            const f4* xr3 = xr0 + 96;
            const f4* xv4 = (const f4*)x16_h2;
#pragma unroll 4
            for (int kc = 0; kc < 32; ++kc) {
                f4 xv = xv4[kc];
                f4 w0 = xr0[kc], w1 = xr1[kc], w2 = xr2[kc], w3 = xr3[kc];
                const h2* xpv = (const h2*)&xv;
                const h2* p0 = (const h2*)&w0; const h2* p1 = (const h2*)&w1;
                const h2* p2 = (const h2*)&w2; const h2* p3 = (const h2*)&w3;
#pragma unroll
                for (int u = 0; u < 4; ++u) {
                    a0 = __builtin_amdgcn_fdot2(p0[u], xpv[u], a0, false);
                    a1 = __builtin_amdgcn_fdot2(p1[u], xpv[u], a1, false);
                    a2 = __builtin_amdgcn_fdot2(p2[u], xpv[u], a2, false);
                    a3 = __builtin_amdgcn_fdot2(p3[u], xpv[u], a3, false);
                }
            }
        }
        {
            const f4* hx4 = (const f4*)hx_h2;
            const f4* r0 = w1r;
            const f4* r1 = w1r + 64;
            const f4* r2 = w1r + 128;
            const f4* r3 = w1r + 192;
#pragma unroll 4
            for (int kc = 0; kc < 64; ++kc) {
                f4 hv = hx4[kc];
                f4 w0 = r0[kc], w1 = r1[kc], w2 = r2[kc], w3 = r3[kc];
                const h2* hp = (const h2*)&hv;
                const h2* p0 = (const h2*)&w0; const h2* p1 = (const h2*)&w1;
                const h2* p2 = (const h2*)&w2; const h2* p3 = (const h2*)&w3;
#pragma unroll
                for (int u = 0; u < 4; ++u) {
                    a0 = __builtin_amdgcn_fdot2(p0[u], hp[u], a0, false);
                    a1 = __builtin_amdgcn_fdot2(p1[u], hp[u], a1, false);
                    a2 = __builtin_amdgcn_fdot2(p2[u], hp[u], a2, false);
                    a3 = __builtin_amdgcn_fdot2(p3[u], hp[u], a3, false);
                }
            }
        }
        g_ld[j0] = a0; g_ld[j0 + 1] = a1; g_ld[j0 + 2] = a2; g_ld[j0 + 3] = a3;
        __syncthreads();

        if (tid < 128) {
            float m0 = sigf(g_ld[pkm(2 * tid)]);
            float m1 = sigf(g_ld[pkm(2 * tid + 1)]);
            h2 p;
            p[0] = (_Float16)(m0 * x_ld[2 * tid]);
            p[1] = (_Float16)(m1 * x_ld[2 * tid + 1]);
            modx_h2[tid] = p;
        } else if (tid < 640) {
            int u = tid - 128;
            float fs = sigf(g_ld[pk5(0, u)]);
            float fl = sigf(g_ld[pk5(1, u)]);
            float al = sigf(g_ld[pk5(2, u)]);
            f_ld[u] = al * fs + (1.0f - al) * fl;
            o_ld[u] = sigf(g_ld[pk5(3, u)]);
        }
        __syncthreads();

        if (tid < 512) {
            float s = g_ld[pk5(4, tid)];
            const f4* w2r = (const f4*)(W2 + (size_t)tid * 256);
            const f4* mx4 = (const f4*)modx_h2;
#pragma unroll 4
            for (int kc = 0; kc < 32; ++kc) {
                f4 wv = w2r[kc];
                f4 mv = mx4[kc];
                const h2* wp = (const h2*)&wv;
                const h2* mp = (const h2*)&mv;
#pragma unroll
                for (int u = 0; u < 4; ++u)
                    s = __builtin_amdgcn_fdot2(wp[u], mp[u], s, false);
            }
            float ch = tanhfast(s);
            float f  = f_ld[tid];
            float cc = f * c_ld[tid] + (1.0f - f) * ch;
            c_ld[tid] = cc;
            float h  = o_ld[tid] * tanhfast(cc);
            h_ld[tid] = h;
            orow[t * UU + tid] = h;
        }
        __syncthreads();
    }
}

// =====================================================================
extern "C" void kernel_launch(void* const* d_in, const int* in_sizes, int n_in,
                              void* d_out, int out_size, void* d_ws, size_t ws_size,
                              hipStream_t stream)
{
    (void)in_sizes; (void)n_in; (void)out_size;
    const float* x   = (const float*)d_in[0];
    const float* h0  = (const float*)d_in[1];
    const float* c0  = (const float*)d_in[2];
    const float* Wfs = (const float*)d_in[3];
    const float* bfs = (const float*)d_in[4];
    const float* Wfl = (const float*)d_in[5];
    const float* bfl = (const float*)d_in[6];
    const float* Wal = (const float*)d_in[7];
    const float* bal = (const float*)d_in[8];
    const float* Wm  = (const float*)d_in[9];
    const float* bm  = (const float*)d_in[10];
    const float* WC  = (const float*)d_in[11];
    const float* bC  = (const float*)d_in[12];
    const float* Wo  = (const float*)d_in[13];
    const float* bo  = (const float*)d_in[14];

    char* ws = (char*)d_ws;
    _Float16* W1   = (_Float16*)(ws + OFF_W1);
    _Float16* W2   = (_Float16*)(ws + OFF_W2);
    _Float16* WxT  = (_Float16*)(ws + OFF_WX);
    float*    b1   = (float*)   (ws + OFF_B1);
    _Float16* hbuf = (_Float16*)(ws + OFF_HB);
    _Float16* mxbf = (_Float16*)(ws + OFF_MX);
    u32*      ctr  = (u32*)     (ws + OFF_CTR);
    _Float16* Xpre = (_Float16*)(ws + OFF_XPRE);

    repack_kernel<<<dim3(1024), dim3(256), 0, stream>>>(
        Wfs, Wfl, Wal, Wm, WC, Wo, bfs, bfl, bal, bm, bC, bo, W1, W2, WxT, b1, ctr);

    if (ws_size >= WS_FULL) {
        xpre_kernel<<<dim3(256, 18), dim3(256), 0, stream>>>(x, WxT, Xpre);
        rnn_coop<<<dim3(NBLK), dim3(256), 0, stream>>>(
            x, h0, c0, W1, W2, b1, Xpre, hbuf, mxbf, ctr, (float*)d_out);
    } else {
        rnn_fb<<<dim3(BB), dim3(704), 0, stream>>>(
            x, h0, c0, W1, W2, WxT, b1, (float*)d_out);
    }
}

// Round 6
// 4054.779 us; speedup vs baseline: 2.9443x; 1.1061x over previous
//
#include <hip/hip_runtime.h>
#include <hip/hip_fp16.h>
#include <math.h>

typedef _Float16 h2 __attribute__((ext_vector_type(2)));
typedef _Float16 h8 __attribute__((ext_vector_type(8)));
typedef float    f4 __attribute__((ext_vector_type(4)));
typedef unsigned short     u16;
typedef unsigned int       u32;
typedef unsigned long long u64;

#define BB 64
#define TT 512
#define DD 256
#define UU 512

#define NBLK 64
#define CPB  44   // packed gate-cols per block: 8*{fs,fl,al,o,WCh} + 4 m
#define XPB  36   // of those, cols with an x-contribution (32 gate + 4 m)
#define UPB  8    // h/c columns owned per block
#define MPB  4    // m (x-dim) columns owned per block
#define NJ   2816
#define NJX  2304

// ---------- ws layout (bytes) ----------
#define OFF_W1   0ull                              // f16 [2816][512] packed, K-contig
#define OFF_W2   (OFF_W1 + 2816ull*512*2)          // f16 [512][256]
#define OFF_WX   (OFF_W2 + 512ull*256*2)           // f16 [2304][256] packed
#define OFF_B1   (OFF_WX + 2304ull*256*2)          // f32 [2816] packed
#define OFF_HB   (OFF_B1 + 2816ull*4)              // u64 hrec [256 j][64 br]
#define OFF_MX   (OFF_HB + 256ull*64*8)            // u64 mrec [128 j][64 br]
#define OFF_CTR  (OFF_MX + 128ull*64*8)            // legacy slot (unused)
#define OFF_XPRE (OFF_CTR + 16400ull*4)            // f16 [512][2304][64]
#define WS_FULL  (OFF_XPRE + 512ull*2304*64*2)     // ~155.6 MB

__device__ __forceinline__ float sigf(float v)     { return 1.0f / (1.0f + __expf(-v)); }
__device__ __forceinline__ float tanhfast(float v) { return 1.0f - 2.0f / (__expf(2.0f * v) + 1.0f); }

// [2 x f16 payload | u32 tag] in one single-copy-atomic u64
__device__ __forceinline__ u64 pack_rec(float a, float b, u32 tag) {
    _Float16 ha = (_Float16)a, hb = (_Float16)b;
    u16 ua, ub;
    __builtin_memcpy(&ua, &ha, 2);
    __builtin_memcpy(&ub, &hb, 2);
    return (u64)((u32)ua | ((u32)ub << 16)) | ((u64)tag << 32);
}

// packed-order helpers (fallback path)
__device__ __forceinline__ int pk5(int g, int u) { return (u >> 3) * 44 + g * 8 + (u & 7); }
__device__ __forceinline__ int pkm(int d)        { return (d >> 2) * 44 + 40 + (d & 3); }

// =====================================================================
// Kernel 1: repack weights into packed block-sliced f16 layouts; prefill
// tagged h records from h0 (tag 1); zero tagged mx records.
// =====================================================================
__global__ void repack_kernel(const float* __restrict__ Wfs, const float* __restrict__ Wfl,
                              const float* __restrict__ Wal, const float* __restrict__ Wm,
                              const float* __restrict__ WC,  const float* __restrict__ Wo,
                              const float* __restrict__ bfs, const float* __restrict__ bfl,
                              const float* __restrict__ bal, const float* __restrict__ bm,
                              const float* __restrict__ bC,  const float* __restrict__ bo,
                              const float* __restrict__ h0,
                              _Float16* __restrict__ W1, _Float16* __restrict__ W2,
                              _Float16* __restrict__ WxT, float* __restrict__ b1,
                              u64* __restrict__ hrec, u64* __restrict__ mrec)
{
    const int stride = gridDim.x * blockDim.x;
    const int idx = blockIdx.x * blockDim.x + threadIdx.x;

    for (int i = idx; i < 2816 * 512; i += stride) {
        int J = i >> 9, k = i & 511;
        int blk = J / 44, c = J - blk * 44;
        float v;
        if (c < 40) {
            int grp = c >> 3, u = blk * 8 + (c & 7);
            const float* Wg = (grp == 0) ? Wfs : (grp == 1) ? Wfl : (grp == 2) ? Wal : (grp == 3) ? Wo : WC;
            v = Wg[(size_t)k * 512 + u];
        } else {
            int d = blk * 4 + (c - 40);
            v = Wm[(size_t)k * 256 + d];
        }
        W1[i] = (_Float16)v;
    }
    for (int i = idx; i < 512 * 256; i += stride) {
        int u = i >> 8, dd = i & 255;
        W2[i] = (_Float16)WC[(size_t)(512 + dd) * 512 + u];
    }
    for (int i = idx; i < 2304 * 256; i += stride) {
        int Jx = i >> 8, k2 = i & 255;
        int blk = Jx / 36, lc = Jx - blk * 36;
        float v;
        if (lc < 32) {
            int grp = lc >> 3, u = blk * 8 + (lc & 7);
            const float* Wg = (grp == 0) ? Wfs : (grp == 1) ? Wfl : (grp == 2) ? Wal : Wo;
            v = Wg[(size_t)(512 + k2) * 512 + u];
        } else {
            int d = blk * 4 + (lc - 32);
            v = Wm[(size_t)(512 + k2) * 256 + d];
        }
        WxT[i] = (_Float16)v;
    }
    for (int J = idx; J < 2816; J += stride) {
        int blk = J / 44, c = J - blk * 44;
        float v;
        if (c < 40) {
            int grp = c >> 3, u = blk * 8 + (c & 7);
            v = (grp == 0) ? bfs[u] : (grp == 1) ? bfl[u] : (grp == 2) ? bal[u] : (grp == 3) ? bo[u] : bC[u];
        } else {
            v = bm[blk * 4 + (c - 40)];
        }
        b1[J] = v;
    }
    // prefill h records (tag 1) from h0: rec (j, br) = {h0[br][2j], h0[br][2j+1]}
    for (int i = idx; i < 256 * 64; i += stride) {
        int j = i >> 6, b = i & 63;
        float v0 = h0[(size_t)b * UU + 2 * j];
        float v1 = h0[(size_t)b * UU + 2 * j + 1];
        hrec[(size_t)j * 64 + b] = pack_rec(v0, v1, 1u);
    }
    // zero mx records (tag 0 never matches an expected tag >= 1)
    for (int i = idx; i < 128 * 64; i += stride) mrec[i] = 0ull;
}

// =====================================================================
// Kernel 2: Xpre = x @ W_x via MFMA.  [32768,256]@[256,2304] -> f16
// output layout [t][Jx][b].
// =====================================================================
__global__ __launch_bounds__(256) void xpre_kernel(const float* __restrict__ x,
                                                   const _Float16* __restrict__ WxT,
                                                   _Float16* __restrict__ Xpre)
{
    __shared__ _Float16 As[128 * 32];
    __shared__ _Float16 Bs[128 * 32];

    const int tid  = threadIdx.x;
    const int lane = tid & 63;
    const int w    = tid >> 6;
    const int wm   = w >> 1, wn = w & 1;
    const int quad = lane >> 4, l16 = lane & 15;
    const int row0 = blockIdx.x * 128;
    const int n0   = blockIdx.y * 128;

    f4 acc[4][4];
    for (int i = 0; i < 4; ++i)
        for (int j = 0; j < 4; ++j)
            acc[i][j] = (f4){0.f, 0.f, 0.f, 0.f};

    for (int kt = 0; kt < 8; ++kt) {
        const int k0 = kt * 32;
        {
            int r  = tid >> 3;
            int cg = (tid & 7) * 4;
            for (int rr = r; rr < 128; rr += 32) {
                f4 v = *(const f4*)&x[(size_t)(row0 + rr) * 256 + k0 + cg];
                As[rr * 32 + cg + 0] = (_Float16)v.x;
                As[rr * 32 + cg + 1] = (_Float16)v.y;
                As[rr * 32 + cg + 2] = (_Float16)v.z;
                As[rr * 32 + cg + 3] = (_Float16)v.w;
            }
        }
        {
            int r   = tid & 127;
            int seg = (tid >> 7) * 16;
            const _Float16* src = &WxT[(size_t)(n0 + r) * 256 + k0 + seg];
            *(f4*)&Bs[r * 32 + seg]     = *(const f4*)src;
            *(f4*)&Bs[r * 32 + seg + 8] = *(const f4*)(src + 8);
        }
        __syncthreads();

        h8 af[4], bfr[4];
#pragma unroll
        for (int f = 0; f < 4; ++f) {
            af[f]  = *(const h8*)&As[(wm * 64 + f * 16 + l16) * 32 + quad * 8];
            bfr[f] = *(const h8*)&Bs[(wn * 64 + f * 16 + l16) * 32 + quad * 8];
        }
#pragma unroll
        for (int fm = 0; fm < 4; ++fm)
#pragma unroll
            for (int fn = 0; fn < 4; ++fn)
                acc[fm][fn] = __builtin_amdgcn_mfma_f32_16x16x32_f16(af[fm], bfr[fn], acc[fm][fn], 0, 0, 0);
        __syncthreads();
    }

#pragma unroll
    for (int fm = 0; fm < 4; ++fm)
#pragma unroll
        for (int fn = 0; fn < 4; ++fn)
#pragma unroll
            for (int r = 0; r < 4; ++r) {
                int rr = row0 + wm * 64 + fm * 16 + quad * 4 + r;  // x row = b*T+t
                int J  = n0 + wn * 64 + fn * 16 + l16;
                int b = rr >> 9, tt = rr & 511;
                Xpre[((size_t)tt * NJX + J) * 64 + b] = (_Float16)acc[fm][fn][r];
            }
}

// =====================================================================
// Kernel 3: cooperative scan, 4 independent wave-planes + single-RTT
// tagged-record exchange in [j][br] layout (coalesced LLC-direct loads).
// 64 blocks x 256 thr. Wave q owns batch rows 16q..16q+15 end-to-end.
// Per step per wave:
//   tagged gather h(t-1) (64 coalesced u64 atomic loads; tag==t+1; the
//   gather IS the wait) -> acc2 -> quad2 publishes mod_x records (2 u64
//   stores, fire-and-forget: no vmcnt, no flag) -> acc0/acc1 -> register
//   elementwise (2 shfl_xor) -> tagged gather mx (32 loads; tag==t+1) ->
//   GEMM2 -> c,h update in regs -> publish h records (tag t+2, fire-and-
//   forget) -> out store. ZERO barriers, flags, drains, or invs in loop.
// Overwrite safety per (j,br) plane: h(t+1) publish requires mx(t+1)
// gather, which requires same-plane h(t) gathers complete (R2/R5-proven
// recurrence argument); exact-tag check.
// =====================================================================
__global__ __launch_bounds__(256, 1) void rnn_coop(
    const float* __restrict__ x, const float* __restrict__ c0,
    const _Float16* __restrict__ W1, const _Float16* __restrict__ W2,
    const float* __restrict__ b1, const _Float16* __restrict__ Xpre,
    u64* __restrict__ hrec, u64* __restrict__ mrec,
    float* __restrict__ out)
{
    __shared__ __align__(16) _Float16 sW1[48 * 512];  // 48 KB, resident all steps
    __shared__ float sB1[44];

    const int tid  = threadIdx.x;
    const int blk  = blockIdx.x;
    const int lane = tid & 63;
    const int q    = tid >> 6;       // wave = batch-quarter plane
    const int l16  = lane & 15;
    const int quad = lane >> 4;
    const int swz  = l16 & 7;
    const int br   = q * 16 + l16;   // global batch row owned in MFMA frags

    // ---- stage W1 slice (44 rows + 4 zero-pad) with chunk swizzle ----
    for (int idx = tid; idx < 48 * 64; idx += 256) {
        int r = idx >> 6, j = idx & 63;
        h8 v = {};
        if (r < CPB) v = *(const h8*)(W1 + ((size_t)(blk * CPB + r) * 512 + j * 8));
        *(h8*)&sW1[(r * 64 + (j ^ (r & 7))) * 8] = v;
    }
    // ---- W2 A-frags in registers (rows u<8 via l16, pad to 16) ----
    h8 af2[8];
#pragma unroll
    for (int ks = 0; ks < 8; ++ks) {
        af2[ks] = (h8){};
        if (l16 < 8)
            af2[ks] = *(const h8*)(W2 + (size_t)(blk * UPB + l16) * 256 + ks * 32 + quad * 8);
    }
    if (tid < CPB) sB1[tid] = b1[blk * CPB + tid];
    // ---- c state in registers: quad<2 lane holds c[u=quad*4+r][b=br] ----
    float cr[4] = {0.f, 0.f, 0.f, 0.f};
    if (quad < 2) {
#pragma unroll
        for (int r = 0; r < 4; ++r)
            cr[r] = c0[(size_t)br * UU + blk * UPB + quad * 4 + r];
    }
    __syncthreads();                      // LDS init ready (h0 prefilled by repack)

    for (int t = 0; t < TT; ++t) {
        const u32 expt = (u32)t + 1u;

        // ---- prefetch read-only operands (overlap the gather) ----
        float pfs[4], pflv[4], pal[4], pov[4];
        float pxm[4] = {0.f, 0.f, 0.f, 0.f};
        f4 pxv = {0.f, 0.f, 0.f, 0.f};
        if (quad < 2) {
            const _Float16* xp = Xpre + ((size_t)t * NJX + blk * XPB) * 64 + br;
#pragma unroll
            for (int r = 0; r < 4; ++r) {
                int u = quad * 4 + r;
                pfs[r]  = (float)xp[(size_t)u * 64];
                pflv[r] = (float)xp[(size_t)(8 + u) * 64];
                pal[r]  = (float)xp[(size_t)(16 + u) * 64];
                pov[r]  = (float)xp[(size_t)(24 + u) * 64];
            }
        } else if (quad == 2) {
            const _Float16* xq = Xpre + ((size_t)t * NJX + blk * XPB + 32) * 64 + br;
#pragma unroll
            for (int r = 0; r < 4; ++r) pxm[r] = (float)xq[(size_t)r * 64];
            pxv = *(const f4*)&x[((size_t)br * TT + t) * DD + blk * MPB];
        }

        // ---- tagged gather of h(t-1): the gather IS the wait ----
        // frag ks needs f16 u-range (ks*4+quad)*8..+7 = records j0..j0+3,
        // j0 = (ks*4+quad)*4; rec addr (j*64 + br)*8 — per-instruction
        // lanes cover 4 x 128B contiguous segments (coalesced).
        h8 bf[16];
        {
            u32 guard = 0;
            for (;;) {
                u32 bad = 0;
#pragma unroll
                for (int ks = 0; ks < 16; ++ks) {
                    const int j0 = (ks * 4 + quad) * 4;
                    u64 r0 = __hip_atomic_load(hrec + (size_t)(j0 + 0) * 64 + br,
                                               __ATOMIC_RELAXED, __HIP_MEMORY_SCOPE_AGENT);
                    u64 r1 = __hip_atomic_load(hrec + (size_t)(j0 + 1) * 64 + br,
                                               __ATOMIC_RELAXED, __HIP_MEMORY_SCOPE_AGENT);
                    u64 r2 = __hip_atomic_load(hrec + (size_t)(j0 + 2) * 64 + br,
                                               __ATOMIC_RELAXED, __HIP_MEMORY_SCOPE_AGENT);
                    u64 r3 = __hip_atomic_load(hrec + (size_t)(j0 + 3) * 64 + br,
                                               __ATOMIC_RELAXED, __HIP_MEMORY_SCOPE_AGENT);
                    bad |= ((u32)(r0 >> 32) ^ expt) | ((u32)(r1 >> 32) ^ expt)
                         | ((u32)(r2 >> 32) ^ expt) | ((u32)(r3 >> 32) ^ expt);
                    u32 d[4] = {(u32)r0, (u32)r1, (u32)r2, (u32)r3};
                    __builtin_memcpy(&bf[ks], d, 16);
                }
                if (__all(bad == 0)) break;
                __builtin_amdgcn_s_sleep(2);
                if (++guard > 1000000u) break;   // safety valve
            }
        }

        // ---- acc2: rows 32..47 = WCh(32..39) + m(40..43) ----
        f4 acc2 = {0.f, 0.f, 0.f, 0.f};
#pragma unroll
        for (int ks = 0; ks < 16; ++ks) {
            int jx = (ks * 4 + quad) ^ swz;
            h8 a2 = *(const h8*)&sW1[((32 + l16) * 64 + jx) * 8];
            acc2 = __builtin_amdgcn_mfma_f32_16x16x32_f16(a2, bf[ks], acc2, 0, 0, 0);
        }
        // mod_x from regs: quad2 lane holds preact[d=blk*4+r][br].
        // Publish as tagged records — fire-and-forget.
        if (quad == 2) {
            float m0 = sigf(acc2[0] + sB1[40] + pxm[0]) * pxv[0];
            float m1 = sigf(acc2[1] + sB1[41] + pxm[1]) * pxv[1];
            float m2 = sigf(acc2[2] + sB1[42] + pxm[2]) * pxv[2];
            float m3 = sigf(acc2[3] + sB1[43] + pxm[3]) * pxv[3];
            __hip_atomic_store(mrec + (size_t)(blk * 2 + 0) * 64 + br, pack_rec(m0, m1, expt),
                               __ATOMIC_RELAXED, __HIP_MEMORY_SCOPE_AGENT);
            __hip_atomic_store(mrec + (size_t)(blk * 2 + 1) * 64 + br, pack_rec(m2, m3, expt),
                               __ATOMIC_RELAXED, __HIP_MEMORY_SCOPE_AGENT);
        }

        // ---- acc0/acc1: rows 0..31; mx stores fly underneath ----
        f4 acc0 = {0.f, 0.f, 0.f, 0.f}, acc1 = {0.f, 0.f, 0.f, 0.f};
#pragma unroll
        for (int ks = 0; ks < 16; ++ks) {
            int jx = (ks * 4 + quad) ^ swz;
            h8 a0 = *(const h8*)&sW1[((     l16) * 64 + jx) * 8];
            h8 a1 = *(const h8*)&sW1[((16 + l16) * 64 + jx) * 8];
            acc0 = __builtin_amdgcn_mfma_f32_16x16x32_f16(a0, bf[ks], acc0, 0, 0, 0);
            acc1 = __builtin_amdgcn_mfma_f32_16x16x32_f16(a1, bf[ks], acc1, 0, 0, 0);
        }

        // ---- elementwise fully in registers (2 shfl per r) ----
        float fv[4], ov[4], cpv[4];
#pragma unroll
        for (int r = 0; r < 4; ++r) {
            float flsh = __shfl_xor(acc0[r], 32);
            float osh  = __shfl_xor(acc1[r], 32);
            if (quad < 2) {
                int u = quad * 4 + r;
                float fs = sigf(acc0[r] + sB1[u]      + pfs[r]);
                float fl = sigf(flsh    + sB1[8 + u]  + pflv[r]);
                float al = sigf(acc1[r] + sB1[16 + u] + pal[r]);
                fv[r]  = al * fs + (1.0f - al) * fl;
                ov[r]  = sigf(osh + sB1[24 + u] + pov[r]);
                cpv[r] = acc2[r] + sB1[32 + u];
            }
        }

        // ---- tagged gather of mod_x ----
        h8 bf2[8];
        {
            u32 guard = 0;
            for (;;) {
                u32 bad = 0;
#pragma unroll
                for (int ks = 0; ks < 8; ++ks) {
                    const int j0 = (ks * 4 + quad) * 4;
                    u64 r0 = __hip_atomic_load(mrec + (size_t)(j0 + 0) * 64 + br,
                                               __ATOMIC_RELAXED, __HIP_MEMORY_SCOPE_AGENT);
                    u64 r1 = __hip_atomic_load(mrec + (size_t)(j0 + 1) * 64 + br,
                                               __ATOMIC_RELAXED, __HIP_MEMORY_SCOPE_AGENT);
                    u64 r2 = __hip_atomic_load(mrec + (size_t)(j0 + 2) * 64 + br,
                                               __ATOMIC_RELAXED, __HIP_MEMORY_SCOPE_AGENT);
                    u64 r3 = __hip_atomic_load(mrec + (size_t)(j0 + 3) * 64 + br,
                                               __ATOMIC_RELAXED, __HIP_MEMORY_SCOPE_AGENT);
                    bad |= ((u32)(r0 >> 32) ^ expt) | ((u32)(r1 >> 32) ^ expt)
                         | ((u32)(r2 >> 32) ^ expt) | ((u32)(r3 >> 32) ^ expt);
                    u32 d[4] = {(u32)r0, (u32)r1, (u32)r2, (u32)r3};
                    __builtin_memcpy(&bf2[ks], d, 16);
                }
                if (__all(bad == 0)) break;
                __builtin_amdgcn_s_sleep(2);
                if (++guard > 1000000u) break;
            }
        }

        // ---- GEMM2: W2(regs) x mod_x(regs) ----
        f4 aq = {0.f, 0.f, 0.f, 0.f};
#pragma unroll
        for (int ks = 0; ks < 8; ++ks)
            aq = __builtin_amdgcn_mfma_f32_16x16x32_f16(af2[ks], bf2[ks], aq, 0, 0, 0);

        // ---- state update in regs; publish h records; out store ----
        if (quad < 2) {
            float hv[4];
#pragma unroll
            for (int r = 0; r < 4; ++r) {
                float ch = tanhfast(aq[r] + cpv[r]);
                float f  = fv[r];
                float c  = f * cr[r] + (1.0f - f) * ch;
                cr[r] = c;
                hv[r] = ov[r] * tanhfast(c);
            }
            const u32 tagh = (u32)t + 2u;
            const int j0 = blk * 4 + quad * 2;
            __hip_atomic_store(hrec + (size_t)(j0 + 0) * 64 + br, pack_rec(hv[0], hv[1], tagh),
                               __ATOMIC_RELAXED, __HIP_MEMORY_SCOPE_AGENT);
            __hip_atomic_store(hrec + (size_t)(j0 + 1) * 64 + br, pack_rec(hv[2], hv[3], tagh),
                               __ATOMIC_RELAXED, __HIP_MEMORY_SCOPE_AGENT);
            f4 ovec = {hv[0], hv[1], hv[2], hv[3]};
            __builtin_nontemporal_store(ovec,
                (f4*)&out[((size_t)br * TT + t) * UU + blk * UPB + quad * 4]);
        }
    }
}

// =====================================================================
// Fallback (small ws): per-batch dot2 scan on packed weights.
// =====================================================================
__global__ __launch_bounds__(704) void rnn_fb(const float* __restrict__ x,
                                              const float* __restrict__ h0,
                                              const float* __restrict__ c0,
                                              const _Float16* __restrict__ W1,
                                              const _Float16* __restrict__ W2,
                                              const _Float16* __restrict__ WxT,
                                              const float* __restrict__ b1g,
                                              float* __restrict__ out)
{
    __shared__ float g_ld[2816];
    __shared__ float b1_ld[2816];
    __shared__ float h_ld[512];
    __shared__ float x_ld[256];
    __shared__ float f_ld[512];
    __shared__ float o_ld[512];
    __shared__ float c_ld[512];
    __shared__ __align__(16) h2 hx_h2[256];
    __shared__ __align__(16) h2 x16_h2[128];
    __shared__ __align__(16) h2 modx_h2[128];

    const int tid = threadIdx.x;
    const int b   = blockIdx.x;
    const int j0  = tid * 4;
    const int c   = j0 % 44;
    const bool hasx = (c < 32) || (c >= 40);
    const int Jx0 = (j0 / 44) * 36 + (c < 32 ? c : c - 8);

    for (int j = tid; j < 2816; j += 704) b1_ld[j] = b1g[j];
    if (tid < 512) {
        h_ld[tid] = h0[b * 512 + tid];
        c_ld[tid] = c0[b * 512 + tid];
    }
    __syncthreads();

    const f4* __restrict__ w1r = (const f4*)(W1 + (size_t)j0 * 512);
    const float* __restrict__ xrow = x + (size_t)b * TT * DD;
    float* __restrict__ orow = out + (size_t)b * TT * UU;

    for (int t = 0; t < TT; ++t) {
        if (tid < 256) {
            h2 p; p[0] = (_Float16)h_ld[2 * tid]; p[1] = (_Float16)h_ld[2 * tid + 1];
            hx_h2[tid] = p;
        } else if (tid < 384) {
            int i = tid - 256;
            float v0 = xrow[t * DD + 2 * i];
            float v1 = xrow[t * DD + 2 * i + 1];
            x_ld[2 * i] = v0; x_ld[2 * i + 1] = v1;
            h2 p; p[0] = (_Float16)v0; p[1] = (_Float16)v1;
            x16_h2[i] = p;
        }
        __syncthreads();

        float a0 = b1_ld[j0], a1 = b1_ld[j0 + 1], a2 = b1_ld[j0 + 2], a3 = b1_ld[j0 + 3];
        if (hasx) {
            const f4* xr0 = (const f4*)(WxT + (size_t)Jx0 * 256);
            const f4* xr1 = xr0 + 32;
            const f4* xr2 = xr0 + 64;
            const f4* xr3 = xr0 + 96;
            const f4* xv4 = (const f4*)x16_h2;
#pragma unroll 4
            for (int kc = 0; kc < 32; ++kc) {
                f4 xv = xv4[kc];
                f4 w0 = xr0[kc], w1 = xr1[kc], w2 = xr2[kc], w3 = xr3[kc];
                const h2* xpv = (const h2*)&xv;
                const h2* p0 = (const h2*)&w0; const h2* p1 = (const h2*)&w1;
                const h2* p2 = (const h2*)&w2; const h2* p3 = (const h2*)&w3;
#pragma unroll
                for (int u = 0; u < 4; ++u) {
                    a0 = __builtin_amdgcn_fdot2(p0[u], xpv[u], a0, false);
                    a1 = __builtin_amdgcn_fdot2(p1[u], xpv[u], a1, false);
                    a2 = __builtin_amdgcn_fdot2(p2[u], xpv[u], a2, false);
                    a3 = __builtin_amdgcn_fdot2(p3[u], xpv[u], a3, false);
                }
            }
        }
        {
            const f4* hx4 = (const f4*)hx_h2;
            const f4* r0 = w1r;
            const f4* r1 = w1r + 64;
            const f4* r2 = w1r + 128;
            const f4* r3 = w1r + 192;
#pragma unroll 4
            for (int kc = 0; kc < 64; ++kc) {
                f4 hv = hx4[kc];
                f4 w0 = r0[kc], w1 = r1[kc], w2 = r2[kc], w3 = r3[kc];
                const h2* hp = (const h2*)&hv;
                const h2* p0 = (const h2*)&w0; const h2* p1 = (const h2*)&w1;
                const h2* p2 = (const h2*)&w2; const h2* p3 = (const h2*)&w3;
#pragma unroll
                for (int u = 0; u < 4; ++u) {
                    a0 = __builtin_amdgcn_fdot2(p0[u], hp[u], a0, false);
                    a1 = __builtin_amdgcn_fdot2(p1[u], hp[u], a1, false);
                    a2 = __builtin_amdgcn_fdot2(p2[u], hp[u], a2, false);
                    a3 = __builtin_amdgcn_fdot2(p3[u], hp[u], a3, false);
                }
            }
        }
        g_ld[j0] = a0; g_ld[j0 + 1] = a1; g_ld[j0 + 2] = a2; g_ld[j0 + 3] = a3;
        __syncthreads();

        if (tid < 128) {
            float m0 = sigf(g_ld[pkm(2 * tid)]);
            float m1 = sigf(g_ld[pkm(2 * tid + 1)]);
            h2 p;
            p[0] = (_Float16)(m0 * x_ld[2 * tid]);
            p[1] = (_Float16)(m1 * x_ld[2 * tid + 1]);
            modx_h2[tid] = p;
        } else if (tid < 640) {
            int u = tid - 128;
            float fs = sigf(g_ld[pk5(0, u)]);
            float fl = sigf(g_ld[pk5(1, u)]);
            float al = sigf(g_ld[pk5(2, u)]);
            f_ld[u] = al * fs + (1.0f - al) * fl;
            o_ld[u] = sigf(g_ld[pk5(3, u)]);
        }
        __syncthreads();

        if (tid < 512) {
            float s = g_ld[pk5(4, tid)];
            const f4* w2r = (const f4*)(W2 + (size_t)tid * 256);
            const f4* mx4 = (const f4*)modx_h2;
#pragma unroll 4
            for (int kc = 0; kc < 32; ++kc) {
                f4 wv = w2r[kc];
                f4 mv = mx4[kc];
                const h2* wp = (const h2*)&wv;
                const h2* mp = (const h2*)&mv;
#pragma unroll
                for (int u = 0; u < 4; ++u)
                    s = __builtin_amdgcn_fdot2(wp[u], mp[u], s, false);
            }
            float ch = tanhfast(s);
            float f  = f_ld[tid];
            float cc = f * c_ld[tid] + (1.0f - f) * ch;
            c_ld[tid] = cc;
            float h  = o_ld[tid] * tanhfast(cc);
            h_ld[tid] = h;
            orow[t * UU + tid] = h;
        }
        __syncthreads();
    }
}

// =====================================================================
extern "C" void kernel_launch(void* const* d_in, const int* in_sizes, int n_in,
                              void* d_out, int out_size, void* d_ws, size_t ws_size,
                              hipStream_t stream)
{
    (void)in_sizes; (void)n_in; (void)out_size;
    const float* x   = (const float*)d_in[0];
    const float* h0  = (const float*)d_in[1];
    const float* c0  = (const float*)d_in[2];
    const float* Wfs = (const float*)d_in[3];
    const float* bfs = (const float*)d_in[4];
    const float* Wfl = (const float*)d_in[5];
    const float* bfl = (const float*)d_in[6];
    const float* Wal = (const float*)d_in[7];
    const float* bal = (const float*)d_in[8];
    const float* Wm  = (const float*)d_in[9];
    const float* bm  = (const float*)d_in[10];
    const float* WC  = (const float*)d_in[11];
    const float* bC  = (const float*)d_in[12];
    const float* Wo  = (const float*)d_in[13];
    const float* bo  = (const float*)d_in[14];

    char* ws = (char*)d_ws;
    _Float16* W1   = (_Float16*)(ws + OFF_W1);
    _Float16* W2   = (_Float16*)(ws + OFF_W2);
    _Float16* WxT  = (_Float16*)(ws + OFF_WX);
    float*    b1   = (float*)   (ws + OFF_B1);
    u64*      hrec = (u64*)     (ws + OFF_HB);
    u64*      mrec = (u64*)     (ws + OFF_MX);
    _Float16* Xpre = (_Float16*)(ws + OFF_XPRE);

    repack_kernel<<<dim3(1024), dim3(256), 0, stream>>>(
        Wfs, Wfl, Wal, Wm, WC, Wo, bfs, bfl, bal, bm, bC, bo, h0,
        W1, W2, WxT, b1, hrec, mrec);

    if (ws_size >= WS_FULL) {
        xpre_kernel<<<dim3(256, 18), dim3(256), 0, stream>>>(x, WxT, Xpre);
        rnn_coop<<<dim3(NBLK), dim3(256), 0, stream>>>(
            x, c0, W1, W2, b1, Xpre, hrec, mrec, (float*)d_out);
    } else {
        rnn_fb<<<dim3(BB), dim3(704), 0, stream>>>(
            x, h0, c0, W1, W2, WxT, b1, (float*)d_out);
    }
}